// Round 3
// baseline (2684.881 us; speedup 1.0000x reference)
//
#include <hip/hip_runtime.h>
#include <math.h>

#define BGR 32
#define NPER0 1024
#define N0 (BGR * NPER0)
#define FDIM 128
#define EDG 524288
#define K1 512
#define K2 256
#define K3 128
#define N1 (BGR * K1)
#define N2 (BGR * K2)
#define EBLK (EDG / 256)   // edge-binning virtual blocks (2048)
#define EPG (EDG / BGR)    // edges per graph (16384)
#define SXP 36             // sxT row pad (floats): 16B-aligned b128 reads
#define CAP 64             // slots per node (Poisson(16); P(deg>64) ~ 1e-18)
#define GRID 1024          // persistent blocks: 4/CU x 256 CU (LDS 34.8KB, VGPR<=128)
#define RSEC (BGR * FDIM)

// Order-preserving float<->uint encoding (radix keys + atomicMax readout).
__device__ __forceinline__ unsigned enc_f(float v) {
    unsigned u = __float_as_uint(v);
    return (u & 0x80000000u) ? ~u : (u | 0x80000000u);
}
__device__ __forceinline__ float dec_f(unsigned u) {
    return (u & 0x80000000u) ? __uint_as_float(u ^ 0x80000000u) : __uint_as_float(~u);
}

// ---------------------------------------------------------------------------
// LDS union: one 34.8KB region, phase-carved. proj is the max member.
// ---------------------------------------------------------------------------
union SMem {
    struct { float W[4096]; float xT[128 * SXP]; } proj;           // 34816 B
    struct { float sc[NPER0]; unsigned ukey[NPER0]; unsigned hist[256];
             unsigned wtot[4]; unsigned sel[2]; int ctr[2]; } tk;  // 9248 B
    struct { float smax[128]; float ssum[128]; } pool;             // 1 KB
    struct { float sz[256]; float s1[128]; float s2[64]; float s3[16];
             float red[2]; } mlp;                                  // ~1.9 KB
};

// ---------------------------------------------------------------------------
// Grid-wide barrier: per-phase arrival counter (no reuse -> no reset races).
// Device-scope release/acquire + __threadfence for cross-XCD data visibility.
// ---------------------------------------------------------------------------
__device__ __forceinline__ void gbar(unsigned* __restrict__ c, int t) {
    __syncthreads();
    if (t == 0) {
        __threadfence();
        __hip_atomic_fetch_add(c, 1u, __ATOMIC_RELEASE, __HIP_MEMORY_SCOPE_AGENT);
        while (__hip_atomic_load(c, __ATOMIC_ACQUIRE, __HIP_MEMORY_SCOPE_AGENT) <
               (unsigned)GRID) {
            __builtin_amdgcn_s_sleep(2);
        }
        __threadfence();
    }
    __syncthreads();
}

// ---------------------------------------------------------------------------
// Register-tiled projection compute: 32 nodes x 128 feats per tile;
// thread=(feature-quad, node-quad); 4x4 outer product, 2 ds_read_b128/k-step.
// ---------------------------------------------------------------------------
__device__ __forceinline__ void proj_compute(float* __restrict__ hp, int nb, int t,
                                             const float* __restrict__ sW,
                                             const float* __restrict__ sxT) {
    const int fg = t >> 3, ng = t & 7, h = fg >> 3;
    const float* ap = sxT + h * 32 * SXP + ng * 4;
    const float* bp = sW + h * 1024 + (fg & 7) * 4;
    float4 acc0 = {0.f, 0.f, 0.f, 0.f}, acc1 = acc0, acc2 = acc0, acc3 = acc0;
#pragma unroll
    for (int k = 0; k < 32; k++) {
        float4 a = *(const float4*)(ap + k * SXP);
        float4 b = *(const float4*)(bp + k * 32);
        acc0.x = fmaf(a.x, b.x, acc0.x); acc0.y = fmaf(a.x, b.y, acc0.y);
        acc0.z = fmaf(a.x, b.z, acc0.z); acc0.w = fmaf(a.x, b.w, acc0.w);
        acc1.x = fmaf(a.y, b.x, acc1.x); acc1.y = fmaf(a.y, b.y, acc1.y);
        acc1.z = fmaf(a.y, b.z, acc1.z); acc1.w = fmaf(a.y, b.w, acc1.w);
        acc2.x = fmaf(a.z, b.x, acc2.x); acc2.y = fmaf(a.z, b.y, acc2.y);
        acc2.z = fmaf(a.z, b.z, acc2.z); acc2.w = fmaf(a.z, b.w, acc2.w);
        acc3.x = fmaf(a.w, b.x, acc3.x); acc3.y = fmaf(a.w, b.y, acc3.y);
        acc3.z = fmaf(a.w, b.z, acc3.z); acc3.w = fmaf(a.w, b.w, acc3.w);
    }
    float4* op = (float4*)(hp + (size_t)(nb + ng * 4) * FDIM + fg * 4);
    op[0] = acc0; op[32] = acc1; op[64] = acc2; op[96] = acc3;
}

// Staging + compute for one 32-node tile (perm-gather variant when perm!=0).
__device__ __forceinline__ void proj_tile(SMem& sm, int t, int nb,
                                          const float* __restrict__ W,
                                          const float* __restrict__ src,
                                          const int* __restrict__ perm,
                                          const float* __restrict__ mult,
                                          float* __restrict__ hp) {
    __syncthreads();  // LDS WAR guard vs previous virtual iteration
    for (int i = t; i < 4096; i += 256) sm.proj.W[i] = W[i];
    for (int i = t; i < 4096; i += 256) {
        int node = i >> 7, dim = i & 127;
        int nd = nb + node;
        float v = perm ? src[(size_t)perm[nd] * FDIM + dim] * mult[nd]
                       : src[(size_t)nd * FDIM + dim];
        sm.proj.xT[dim * SXP + node] = v;
    }
    __syncthreads();
    proj_compute(hp, nb, t, sm.proj.W, sm.proj.xT);
}

// ---------------------------------------------------------------------------
// Pooling readout: 8 kept nodes per virtual block, 256 threads=(f,half).
// ---------------------------------------------------------------------------
__device__ __forceinline__ void pool8(SMem& sm, const float* __restrict__ ha,
                                      const int* __restrict__ perm,
                                      const float* __restrict__ mult, int k, int pb,
                                      unsigned* __restrict__ rmax,
                                      float* __restrict__ rsum, int t) {
    __syncthreads();  // LDS WAR guard
    const int g = pb & 31, c = pb >> 5;
    const int f = t & 127, half = t >> 7;
    const int base = g * k + c * 8;
    float vmax = -1e30f, vsum = 0.0f;
#pragma unroll
    for (int j0 = 0; j0 < 4; j0++) {
        int newid = base + half + j0 * 2;
        int old = perm[newid];
        float m = mult[newid];
        float v = ha[(size_t)old * FDIM + f] * m;
        vmax = fmaxf(vmax, v);
        vsum += v;
    }
    if (half) { sm.pool.smax[f] = vmax; sm.pool.ssum[f] = vsum; }
    __syncthreads();
    if (!half) {
        vmax = fmaxf(vmax, sm.pool.smax[f]);
        vsum += sm.pool.ssum[f];
        atomicMax(&rmax[g * FDIM + f], enc_f(vmax));
        atomicAdd(&rsum[g * FDIM + f], vsum);
    }
}

// ---------------------------------------------------------------------------
// Slot-list compaction: wave per KEPT node; remap prev slots via nmap,
// ballot-compact. No atomics, no edge rescan.
// ---------------------------------------------------------------------------
__device__ __forceinline__ void comp_node(const int* __restrict__ cnt_prev,
                                          const int* __restrict__ slot_prev,
                                          const int* __restrict__ nmap,
                                          int* __restrict__ cnt_next,
                                          int* __restrict__ slot_next,
                                          const int* __restrict__ perm, int knext,
                                          int vb, int t) {
    const int w = t >> 6, lane = t & 63;
    const int b = (vb & 31) * knext + (vb >> 5) * 4 + w;
    const int old = perm[b];
    const int c = min(cnt_prev[old], CAP);
    int a = -1;
    if (lane < c) a = nmap[slot_prev[(size_t)old * CAP + lane]];
    unsigned long long mk = __ballot(a >= 0);
    if (a >= 0) {
        int pos = __popcll(mk & ((1ull << lane) - 1ull));
        slot_next[(size_t)b * CAP + pos] = a;
    }
    if (lane == 0) cnt_next[b] = __popcll(mk);
}

// ---------------------------------------------------------------------------
// GCN aggregation (gather via slots) + bias + relu + fused attention score.
// Wave per node; lane = 2 features (float2); shfl-broadcast edge prefetch.
// ---------------------------------------------------------------------------
__device__ __forceinline__ void agg_node(const float* __restrict__ hp,
                                         const float* __restrict__ b,
                                         const int* __restrict__ cnt,
                                         const int* __restrict__ slot,
                                         const float* __restrict__ A,
                                         const float* __restrict__ psW,
                                         float* __restrict__ ha,
                                         float* __restrict__ csd, int nper,
                                         int vb, int t) {
    const int w = t >> 6;
    const int lane = t & 63;
    const int g = vb & 31;
    const int chunk = vb >> 5;
    const int i = g * nper + chunk * 4 + w;
    const int ci = cnt[i];
    const float di = rsqrtf((float)ci + 1.0f);
    const int c = min(ci, CAP);
    const float2* __restrict__ hp2 = (const float2*)hp;
    float2 self = hp2[(size_t)i * 64 + lane];
    float accx = self.x * di * di, accy = self.y * di * di;
    int idx = 0;
    float dv = 0.0f;
    if (lane < c) {
        idx = slot[i * CAP + lane];
        dv = rsqrtf((float)cnt[idx] + 1.0f);
    }
    int j = 0;
    for (; j + 3 < c; j += 4) {
        int s0 = __shfl(idx, j, 64);
        int s1 = __shfl(idx, j + 1, 64);
        int s2 = __shfl(idx, j + 2, 64);
        int s3 = __shfl(idx, j + 3, 64);
        float c0 = __shfl(dv, j, 64) * di;
        float c1 = __shfl(dv, j + 1, 64) * di;
        float c2 = __shfl(dv, j + 2, 64) * di;
        float c3 = __shfl(dv, j + 3, 64) * di;
        float2 v0 = hp2[(size_t)s0 * 64 + lane];
        float2 v1 = hp2[(size_t)s1 * 64 + lane];
        float2 v2 = hp2[(size_t)s2 * 64 + lane];
        float2 v3 = hp2[(size_t)s3 * 64 + lane];
        accx = fmaf(v0.x, c0, accx); accy = fmaf(v0.y, c0, accy);
        accx = fmaf(v1.x, c1, accx); accy = fmaf(v1.y, c1, accy);
        accx = fmaf(v2.x, c2, accx); accy = fmaf(v2.y, c2, accy);
        accx = fmaf(v3.x, c3, accx); accy = fmaf(v3.y, c3, accy);
    }
    for (; j < c; j++) {
        int s = __shfl(idx, j, 64);
        float co = __shfl(dv, j, 64) * di;
        float2 v = hp2[(size_t)s * 64 + lane];
        accx = fmaf(v.x, co, accx); accy = fmaf(v.y, co, accy);
    }
    float2 bb = ((const float2*)b)[lane];
    float2 o;
    o.x = fmaxf(accx + bb.x, 0.0f);
    o.y = fmaxf(accy + bb.y, 0.0f);
    ((float2*)ha)[(size_t)i * 64 + lane] = o;
    float2 Av = ((const float2*)A)[lane];
    float2 Pv = ((const float2*)psW)[lane];
    float a = o.x * Av.x + o.y * Av.y;
    float p = o.x * Pv.x + o.y * Pv.y;
#pragma unroll
    for (int d = 8; d > 0; d >>= 1) {
        a += __shfl_down(a, d, 16);
        p += __shfl_down(p, d, 16);
    }
    float part = a * p;                  // heads at lanes 0,16,32,48
    part += __shfl_down(part, 16, 64);
    part += __shfl_down(part, 32, 64);
    if (lane == 0) csd[i] = part * di;   // pre-scaled by dinv[i]
}

// ---------------------------------------------------------------------------
// WIDE score: wave per node, lanes = neighbors; one gather latency + reduce.
// ---------------------------------------------------------------------------
__device__ __forceinline__ void score_node(const float* __restrict__ csd,
                                           const int* __restrict__ cnt,
                                           const int* __restrict__ slot,
                                           const float* __restrict__ psb,
                                           float* __restrict__ scout, int nper,
                                           int vb, int t) {
    const int w = t >> 6;
    const int lane = t & 63;
    const int g = vb & 31;
    const int chunk = vb >> 5;
    const int i = g * nper + chunk * 4 + w;
    const int ci = cnt[i];
    const int c = min(ci, CAP);
    float v = 0.0f;
    if (lane < c) v = csd[slot[(size_t)i * CAP + lane]];
#pragma unroll
    for (int d = 32; d > 0; d >>= 1) v += __shfl_xor(v, d, 64);
    if (lane == 0)
        scout[i] = rsqrtf((float)ci + 1.0f) * (v + csd[i]) + psb[0];
}

// ---------------------------------------------------------------------------
// Per-graph top-k SET via 4-pass radix select (wave digit pre-merge).
// ---------------------------------------------------------------------------
__device__ __forceinline__ void topk_body(SMem& sm, const float* __restrict__ scin,
                                          int nper, int k, int* __restrict__ nmap,
                                          int* __restrict__ perm,
                                          float* __restrict__ mult, int g, int t) {
    __syncthreads();
    const int w = t >> 6, l = t & 63;
    const int gnb = g * nper;
    for (int i = t; i < nper; i += 256) {
        float v = scin[gnb + i];
        sm.tk.sc[i] = v;
        sm.tk.ukey[i] = enc_f(v);
    }
    if (t == 0) { sm.tk.sel[0] = 0u; sm.tk.sel[1] = (unsigned)k; }
    __syncthreads();
    for (int shift = 24; shift >= 0; shift -= 8) {
        sm.tk.hist[t] = 0u;
        __syncthreads();
        const unsigned prefix = sm.tk.sel[0];
        const unsigned need = sm.tk.sel[1];
        for (int i = t; i < nper; i += 256) {
            unsigned u = sm.tk.ukey[i];
            bool inp = (shift == 24) || ((u >> (shift + 8)) == (prefix >> (shift + 8)));
            int dig = inp ? (int)((u >> shift) & 255u) : -1;
            int cv = inp ? 1 : 0;
#pragma unroll
            for (int d = 1; d < 64; d <<= 1) {
                int od = __shfl_xor(dig, d, 64);
                int oc = __shfl_xor(cv, d, 64);
                if (od == dig) cv = ((l & d) == 0) ? (cv + oc) : 0;
            }
            if (dig >= 0 && cv > 0) atomicAdd(&sm.tk.hist[dig], (unsigned)cv);
        }
        __syncthreads();
        const unsigned h = sm.tk.hist[t];
        unsigned s = h;
#pragma unroll
        for (int off = 1; off < 64; off <<= 1) {
            unsigned v = __shfl_down(s, off, 64);
            if (l + off < 64) s += v;
        }
        if (l == 0) sm.tk.wtot[w] = s;
        __syncthreads();
        unsigned add = 0;
        for (int ww = w + 1; ww < 4; ww++) add += sm.tk.wtot[ww];
        const unsigned sfx = s + add;   // #keys with digit >= t (within prefix)
        const unsigned gtr = sfx - h;   // #keys with digit >  t
        if (sfx >= need && gtr < need) {  // exactly one thread
            sm.tk.sel[0] = prefix | ((unsigned)t << shift);
            sm.tk.sel[1] = need - gtr;
        }
        __syncthreads();
    }
    const unsigned T = sm.tk.sel[0];
    const int need = (int)sm.tk.sel[1];
    if (t == 0) { sm.tk.ctr[0] = 0; sm.tk.ctr[1] = k - need; }
    __syncthreads();
    for (int i = t; i < nper; i += 256) {
        unsigned u = sm.tk.ukey[i];
        int node = gnb + i;
        int newid = -1;
        if (u > T) {
            newid = g * k + atomicAdd(&sm.tk.ctr[0], 1);
        } else if (u == T) {
            int slot2 = atomicAdd(&sm.tk.ctr[1], 1);
            if (slot2 < k) newid = g * k + slot2;
        }
        nmap[node] = newid;
        if (newid >= 0) {
            perm[newid] = node;
            mult[newid] = tanhf(sm.tk.sc[i]);
        }
    }
}

// ---------------------------------------------------------------------------
// Final MLP + log_softmax (one virtual block per graph, 256 threads).
// ---------------------------------------------------------------------------
__device__ __forceinline__ void final_body(SMem& sm, const unsigned* __restrict__ rmax,
                                           const float* __restrict__ rsum,
                                           const float* __restrict__ l1W,
                                           const float* __restrict__ l1b,
                                           const float* __restrict__ l2W,
                                           const float* __restrict__ l2b,
                                           const float* __restrict__ l3W,
                                           const float* __restrict__ l3b,
                                           float* __restrict__ out, int g, int t) {
    __syncthreads();
    if (t < 128) {
        sm.mlp.sz[t] = dec_f(rmax[g * FDIM + t]) + dec_f(rmax[RSEC + g * FDIM + t]) +
                       dec_f(rmax[2 * RSEC + g * FDIM + t]);
    } else {
        int f = t - 128;
        sm.mlp.sz[t] = rsum[g * FDIM + f] / (float)K1 +
                       rsum[RSEC + g * FDIM + f] / (float)K2 +
                       rsum[2 * RSEC + g * FDIM + f] / (float)K3;
    }
    __syncthreads();
    if (t < 128) {
        float acc = l1b[t];
        for (int i = 0; i < 256; i++) acc = fmaf(sm.mlp.sz[i], l1W[i * 128 + t], acc);
        sm.mlp.s1[t] = fmaxf(acc, 0.0f);
    }
    __syncthreads();
    if (t < 64) {
        float a2 = l2b[t];
        for (int i = 0; i < 128; i++) a2 = fmaf(sm.mlp.s1[i], l2W[i * 64 + t], a2);
        sm.mlp.s2[t] = fmaxf(a2, 0.0f);
    }
    __syncthreads();
    if (t < 10) {
        float a3 = l3b[t];
        for (int i = 0; i < 64; i++) a3 = fmaf(sm.mlp.s2[i], l3W[i * 10 + t], a3);
        sm.mlp.s3[t] = a3;
    }
    __syncthreads();
    if (t == 0) {
        float m = -1e30f;
        for (int c = 0; c < 10; c++) m = fmaxf(m, sm.mlp.s3[c]);
        float sum = 0.0f;
        for (int c = 0; c < 10; c++) sum += expf(sm.mlp.s3[c] - m);
        sm.mlp.red[0] = m;
        sm.mlp.red[1] = logf(sum);
    }
    __syncthreads();
    if (t < 10) out[g * 10 + t] = sm.mlp.s3[t] - sm.mlp.red[0] - sm.mlp.red[1];
}

// ---------------------------------------------------------------------------
// Parameter block (single by-value kernel arg).
// ---------------------------------------------------------------------------
struct MPar {
    const float *x; const int *src0, *dst0;
    const float *W1, *b1, *A1, *ps1W, *ps1b;
    const float *W2, *b2, *A2, *ps2W, *ps2b;
    const float *W3, *b3, *A3, *ps3W, *ps3b;
    const float *l1W, *l1b, *l2W, *l2b, *l3W, *l3b;
    float *out;
    float *hproj, *hact;
    int *cntA, *cntB, *cntC, *slotA, *slotB, *slotC;
    float *cs, *scb;
    int *nmapA, *nmapB, *nmapC, *perm;
    float *mult;
    unsigned *rmax; float *rsum;
    unsigned *bars;   // 14 per-phase arrival counters (pre-zeroed)
};

// ---------------------------------------------------------------------------
// Persistent mega-kernel: the whole 3-stage pipeline, 14 grid barriers.
// Phase widths are multiples of 32 -> vb&31 == blk&31 (graph->XCD locality).
// ---------------------------------------------------------------------------
__global__ __launch_bounds__(256, 4) void mega(MPar p) {
    __shared__ SMem sm;
    const int blk = blockIdx.x, t = threadIdx.x;

    // P0: zero cntA + readout accumulators
    {
        int i = blk * 256 + t;
        if (i < N0) p.cntA[i] = 0;
        if (i < 3 * RSEC) { p.rmax[i] = 0u; p.rsum[i] = 0.0f; }
    }
    gbar(p.bars + 0, t);

    // P1: edge binning (2048 vb, graph-swizzled) + proj1 (1024 vb)
    for (int vb = blk; vb < EBLK + N0 / 32; vb += GRID) {
        if (vb < EBLK) {
            int g = vb & 31, ch = vb >> 5;
            int e = g * EPG + ch * 256 + t;
            int s = p.src0[e];
            int d = p.dst0[e];
            int q = atomicAdd(&p.cntA[d], 1);
            if (q < CAP) p.slotA[d * CAP + q] = s;
        } else {
            int tb = vb - EBLK;
            int nb = (tb & 31) * NPER0 + (tb >> 5) * 32;
            proj_tile(sm, t, nb, p.W1, p.x, nullptr, nullptr, p.hproj);
        }
    }
    gbar(p.bars + 1, t);

    // P2: agg1
    for (int vb = blk; vb < N0 / 4; vb += GRID)
        agg_node(p.hproj, p.b1, p.cntA, p.slotA, p.A1, p.ps1W, p.hact, p.cs, NPER0, vb, t);
    gbar(p.bars + 2, t);

    // P3: score1
    for (int vb = blk; vb < N0 / 4; vb += GRID)
        score_node(p.cs, p.cntA, p.slotA, p.ps1b, p.scb, NPER0, vb, t);
    gbar(p.bars + 3, t);

    // P4: topk1
    for (int vb = blk; vb < BGR; vb += GRID)
        topk_body(sm, p.scb, NPER0, K1, p.nmapA, p.perm, p.mult, vb, t);
    gbar(p.bars + 4, t);

    // P5: comp2 (4096) + proj2 (512) + pool1 (2048)
    for (int vb = blk; vb < N1 / 4 + N1 / 32 + BGR * K1 / 8; vb += GRID) {
        if (vb < N1 / 4) {
            comp_node(p.cntA, p.slotA, p.nmapA, p.cntB, p.slotB, p.perm, K1, vb, t);
        } else if (vb < N1 / 4 + N1 / 32) {
            int tb = vb - N1 / 4;
            int nb = (tb & 31) * K1 + (tb >> 5) * 32;
            proj_tile(sm, t, nb, p.W2, p.hact, p.perm, p.mult, p.hproj);
        } else {
            pool8(sm, p.hact, p.perm, p.mult, K1, vb - N1 / 4 - N1 / 32,
                  p.rmax, p.rsum, t);
        }
    }
    gbar(p.bars + 5, t);

    // P6: agg2
    for (int vb = blk; vb < N1 / 4; vb += GRID)
        agg_node(p.hproj, p.b2, p.cntB, p.slotB, p.A2, p.ps2W, p.hact, p.cs, K1, vb, t);
    gbar(p.bars + 6, t);

    // P7: score2
    for (int vb = blk; vb < N1 / 4; vb += GRID)
        score_node(p.cs, p.cntB, p.slotB, p.ps2b, p.scb, K1, vb, t);
    gbar(p.bars + 7, t);

    // P8: topk2
    for (int vb = blk; vb < BGR; vb += GRID)
        topk_body(sm, p.scb, K1, K2, p.nmapB, p.perm, p.mult, vb, t);
    gbar(p.bars + 8, t);

    // P9: comp3 (2048) + proj3 (256) + pool2 (1024)
    for (int vb = blk; vb < N2 / 4 + N2 / 32 + BGR * K2 / 8; vb += GRID) {
        if (vb < N2 / 4) {
            comp_node(p.cntB, p.slotB, p.nmapB, p.cntC, p.slotC, p.perm, K2, vb, t);
        } else if (vb < N2 / 4 + N2 / 32) {
            int tb = vb - N2 / 4;
            int nb = (tb & 31) * K2 + (tb >> 5) * 32;
            proj_tile(sm, t, nb, p.W3, p.hact, p.perm, p.mult, p.hproj);
        } else {
            pool8(sm, p.hact, p.perm, p.mult, K2, vb - N2 / 4 - N2 / 32,
                  p.rmax + RSEC, p.rsum + RSEC, t);
        }
    }
    gbar(p.bars + 9, t);

    // P10: agg3
    for (int vb = blk; vb < N2 / 4; vb += GRID)
        agg_node(p.hproj, p.b3, p.cntC, p.slotC, p.A3, p.ps3W, p.hact, p.cs, K2, vb, t);
    gbar(p.bars + 10, t);

    // P11: score3
    for (int vb = blk; vb < N2 / 4; vb += GRID)
        score_node(p.cs, p.cntC, p.slotC, p.ps3b, p.scb, K2, vb, t);
    gbar(p.bars + 11, t);

    // P12: topk3
    for (int vb = blk; vb < BGR; vb += GRID)
        topk_body(sm, p.scb, K2, K3, p.nmapC, p.perm, p.mult, vb, t);
    gbar(p.bars + 12, t);

    // P13: pool3 (512 vb)
    for (int vb = blk; vb < BGR * K3 / 8; vb += GRID)
        pool8(sm, p.hact, p.perm, p.mult, K3, vb, p.rmax + 2 * RSEC,
              p.rsum + 2 * RSEC, t);
    gbar(p.bars + 13, t);

    // P14: final MLP (32 vb)
    for (int vb = blk; vb < BGR; vb += GRID)
        final_body(sm, p.rmax, p.rsum, p.l1W, p.l1b, p.l2W, p.l2b, p.l3W, p.l3b,
                   p.out, vb, t);
}

// ---------------------------------------------------------------------------
extern "C" void kernel_launch(void* const* d_in, const int* in_sizes, int n_in,
                              void* d_out, int out_size, void* d_ws, size_t ws_size,
                              hipStream_t stream) {
    char* ws = (char*)d_ws;
    size_t o = 0;
    auto alloc = [&](size_t bytes) -> void* {
        void* p = ws + o;
        o += (bytes + 255) & ~(size_t)255;
        return p;
    };
    MPar P;
    P.x    = (const float*)d_in[0];
    P.src0 = (const int*)d_in[1];
    P.dst0 = (const int*)d_in[2];
    P.W1 = (const float*)d_in[3];  P.b1 = (const float*)d_in[4];
    P.A1 = (const float*)d_in[5];  P.ps1W = (const float*)d_in[6];
    P.ps1b = (const float*)d_in[7];
    P.W2 = (const float*)d_in[8];  P.b2 = (const float*)d_in[9];
    P.A2 = (const float*)d_in[10]; P.ps2W = (const float*)d_in[11];
    P.ps2b = (const float*)d_in[12];
    P.W3 = (const float*)d_in[13]; P.b3 = (const float*)d_in[14];
    P.A3 = (const float*)d_in[15]; P.ps3W = (const float*)d_in[16];
    P.ps3b = (const float*)d_in[17];
    P.l1W = (const float*)d_in[18]; P.l1b = (const float*)d_in[19];
    P.l2W = (const float*)d_in[20]; P.l2b = (const float*)d_in[21];
    P.l3W = (const float*)d_in[22]; P.l3b = (const float*)d_in[23];
    P.out = (float*)d_out;

    P.hproj = (float*)alloc((size_t)N0 * FDIM * 4);
    P.hact  = (float*)alloc((size_t)N0 * FDIM * 4);
    P.cntA  = (int*)alloc(N0 * 4);
    P.cntB  = (int*)alloc(N1 * 4);
    P.cntC  = (int*)alloc(N2 * 4);
    P.slotA = (int*)alloc((size_t)N0 * CAP * 4);
    P.slotB = (int*)alloc((size_t)N1 * CAP * 4);
    P.slotC = (int*)alloc((size_t)N2 * CAP * 4);
    P.cs    = (float*)alloc(N0 * 4);
    P.scb   = (float*)alloc(N0 * 4);
    P.nmapA = (int*)alloc(N0 * 4);
    P.nmapB = (int*)alloc(N1 * 4);
    P.nmapC = (int*)alloc(N2 * 4);
    P.perm  = (int*)alloc(N1 * 4);
    P.mult  = (float*)alloc(N1 * 4);
    P.rmax  = (unsigned*)alloc(3 * RSEC * 4);
    P.rsum  = (float*)alloc(3 * RSEC * 4);
    P.bars  = (unsigned*)alloc(64);

    hipMemsetAsync(P.bars, 0, 64, stream);
    mega<<<GRID, 256, 0, stream>>>(P);

    (void)in_sizes; (void)n_in; (void)out_size; (void)ws_size;
}

// Round 4
// 1320.168 us; speedup vs baseline: 2.0337x; 2.0337x over previous
//
#include <hip/hip_runtime.h>
#include <math.h>

#define BGR 32
#define NPER0 1024
#define N0 (BGR * NPER0)
#define FDIM 128
#define EDG 524288
#define K1 512
#define K2 256
#define K3 128
#define N1 (BGR * K1)
#define N2 (BGR * K2)
#define EBLK (EDG / 256)   // edge-binning virtual blocks (2048)
#define EPG (EDG / BGR)    // edges per graph (16384)
#define SXP 36             // sxT row pad (floats): 16B-aligned b128 reads
#define CAP 64             // slots per node (Poisson(16); P(deg>64) ~ 1e-18)
#define GRID 1024          // persistent blocks: 4/CU x 256 CU (LDS 34.8KB, VGPR<=128)
#define RSEC (BGR * FDIM)

// Order-preserving float<->uint encoding (radix keys + atomicMax readout).
__device__ __forceinline__ unsigned enc_f(float v) {
    unsigned u = __float_as_uint(v);
    return (u & 0x80000000u) ? ~u : (u | 0x80000000u);
}
__device__ __forceinline__ float dec_f(unsigned u) {
    return (u & 0x80000000u) ? __uint_as_float(u ^ 0x80000000u) : __uint_as_float(~u);
}

// ---------------------------------------------------------------------------
// LDS union: one 34.8KB region, phase-carved. proj is the max member.
// ---------------------------------------------------------------------------
union SMem {
    struct { float W[4096]; float xT[128 * SXP]; } proj;           // 34816 B
    struct { float sc[NPER0]; unsigned ukey[NPER0]; unsigned hist[256];
             unsigned wtot[4]; unsigned sel[2]; int ctr[2]; } tk;  // 9248 B
    struct { float smax[128]; float ssum[128]; } pool;             // 1 KB
    struct { float sz[256]; float s1[128]; float s2[64]; float s3[16];
             float red[2]; } mlp;                                  // ~1.9 KB
};

// ---------------------------------------------------------------------------
// Grid-wide barrier, R3-failure-fixed:
//  - arrival: ONE release fetch_add per block (not per poll)
//  - last arriver sets a write-once flag (separate word)
//  - spinners poll flag with RELAXED agent atomics (sc1: bypasses L2, no
//    buffer_inv per poll -- R3's killer) + s_sleep backoff
//  - exactly ONE acquire fence per block after exit
// bar[0]=arrival count, bar[1]=go flag; fresh pair per phase (no reset races).
// ---------------------------------------------------------------------------
__device__ __forceinline__ void gbar(unsigned* __restrict__ bar, int t) {
    __syncthreads();
    if (t == 0) {
        unsigned prev = __hip_atomic_fetch_add(bar, 1u, __ATOMIC_RELEASE,
                                               __HIP_MEMORY_SCOPE_AGENT);
        if (prev == (unsigned)(GRID - 1)) {
            __hip_atomic_store(bar + 1, 1u, __ATOMIC_RELEASE,
                               __HIP_MEMORY_SCOPE_AGENT);
        } else {
            int it = 0;
            while (__hip_atomic_load(bar + 1, __ATOMIC_RELAXED,
                                     __HIP_MEMORY_SCOPE_AGENT) == 0u) {
                if (it < 4) { __builtin_amdgcn_s_sleep(8); it++; }
                else        { __builtin_amdgcn_s_sleep(64); }
            }
        }
        __builtin_amdgcn_fence(__ATOMIC_ACQUIRE, "agent");
    }
    __syncthreads();
}

// ---------------------------------------------------------------------------
// Register-tiled projection compute: 32 nodes x 128 feats per tile;
// thread=(feature-quad, node-quad); 4x4 outer product, 2 ds_read_b128/k-step.
// ---------------------------------------------------------------------------
__device__ __forceinline__ void proj_compute(float* __restrict__ hp, int nb, int t,
                                             const float* __restrict__ sW,
                                             const float* __restrict__ sxT) {
    const int fg = t >> 3, ng = t & 7, h = fg >> 3;
    const float* ap = sxT + h * 32 * SXP + ng * 4;
    const float* bp = sW + h * 1024 + (fg & 7) * 4;
    float4 acc0 = {0.f, 0.f, 0.f, 0.f}, acc1 = acc0, acc2 = acc0, acc3 = acc0;
#pragma unroll
    for (int k = 0; k < 32; k++) {
        float4 a = *(const float4*)(ap + k * SXP);
        float4 b = *(const float4*)(bp + k * 32);
        acc0.x = fmaf(a.x, b.x, acc0.x); acc0.y = fmaf(a.x, b.y, acc0.y);
        acc0.z = fmaf(a.x, b.z, acc0.z); acc0.w = fmaf(a.x, b.w, acc0.w);
        acc1.x = fmaf(a.y, b.x, acc1.x); acc1.y = fmaf(a.y, b.y, acc1.y);
        acc1.z = fmaf(a.y, b.z, acc1.z); acc1.w = fmaf(a.y, b.w, acc1.w);
        acc2.x = fmaf(a.z, b.x, acc2.x); acc2.y = fmaf(a.z, b.y, acc2.y);
        acc2.z = fmaf(a.z, b.z, acc2.z); acc2.w = fmaf(a.z, b.w, acc2.w);
        acc3.x = fmaf(a.w, b.x, acc3.x); acc3.y = fmaf(a.w, b.y, acc3.y);
        acc3.z = fmaf(a.w, b.z, acc3.z); acc3.w = fmaf(a.w, b.w, acc3.w);
    }
    float4* op = (float4*)(hp + (size_t)(nb + ng * 4) * FDIM + fg * 4);
    op[0] = acc0; op[32] = acc1; op[64] = acc2; op[96] = acc3;
}

// Staging + compute for one 32-node tile (perm-gather variant when perm!=0).
__device__ __forceinline__ void proj_tile(SMem& sm, int t, int nb,
                                          const float* __restrict__ W,
                                          const float* __restrict__ src,
                                          const int* __restrict__ perm,
                                          const float* __restrict__ mult,
                                          float* __restrict__ hp) {
    __syncthreads();  // LDS WAR guard vs previous virtual iteration
    for (int i = t; i < 4096; i += 256) sm.proj.W[i] = W[i];
    for (int i = t; i < 4096; i += 256) {
        int node = i >> 7, dim = i & 127;
        int nd = nb + node;
        float v = perm ? src[(size_t)perm[nd] * FDIM + dim] * mult[nd]
                       : src[(size_t)nd * FDIM + dim];
        sm.proj.xT[dim * SXP + node] = v;
    }
    __syncthreads();
    proj_compute(hp, nb, t, sm.proj.W, sm.proj.xT);
}

// ---------------------------------------------------------------------------
// Pooling readout: 8 kept nodes per virtual block, 256 threads=(f,half).
// ---------------------------------------------------------------------------
__device__ __forceinline__ void pool8(SMem& sm, const float* __restrict__ ha,
                                      const int* __restrict__ perm,
                                      const float* __restrict__ mult, int k, int pb,
                                      unsigned* __restrict__ rmax,
                                      float* __restrict__ rsum, int t) {
    __syncthreads();  // LDS WAR guard
    const int g = pb & 31, c = pb >> 5;
    const int f = t & 127, half = t >> 7;
    const int base = g * k + c * 8;
    float vmax = -1e30f, vsum = 0.0f;
#pragma unroll
    for (int j0 = 0; j0 < 4; j0++) {
        int newid = base + half + j0 * 2;
        int old = perm[newid];
        float m = mult[newid];
        float v = ha[(size_t)old * FDIM + f] * m;
        vmax = fmaxf(vmax, v);
        vsum += v;
    }
    if (half) { sm.pool.smax[f] = vmax; sm.pool.ssum[f] = vsum; }
    __syncthreads();
    if (!half) {
        vmax = fmaxf(vmax, sm.pool.smax[f]);
        vsum += sm.pool.ssum[f];
        atomicMax(&rmax[g * FDIM + f], enc_f(vmax));
        atomicAdd(&rsum[g * FDIM + f], vsum);
    }
}

// ---------------------------------------------------------------------------
// Slot-list compaction: wave per KEPT node; remap prev slots via nmap,
// ballot-compact. No atomics, no edge rescan.
// ---------------------------------------------------------------------------
__device__ __forceinline__ void comp_node(const int* __restrict__ cnt_prev,
                                          const int* __restrict__ slot_prev,
                                          const int* __restrict__ nmap,
                                          int* __restrict__ cnt_next,
                                          int* __restrict__ slot_next,
                                          const int* __restrict__ perm, int knext,
                                          int vb, int t) {
    const int w = t >> 6, lane = t & 63;
    const int b = (vb & 31) * knext + (vb >> 5) * 4 + w;
    const int old = perm[b];
    const int c = min(cnt_prev[old], CAP);
    int a = -1;
    if (lane < c) a = nmap[slot_prev[(size_t)old * CAP + lane]];
    unsigned long long mk = __ballot(a >= 0);
    if (a >= 0) {
        int pos = __popcll(mk & ((1ull << lane) - 1ull));
        slot_next[(size_t)b * CAP + pos] = a;
    }
    if (lane == 0) cnt_next[b] = __popcll(mk);
}

// ---------------------------------------------------------------------------
// GCN aggregation (gather via slots) + bias + relu + fused attention score.
// Wave per node; lane = 2 features (float2); shfl-broadcast edge prefetch.
// ---------------------------------------------------------------------------
__device__ __forceinline__ void agg_node(const float* __restrict__ hp,
                                         const float* __restrict__ b,
                                         const int* __restrict__ cnt,
                                         const int* __restrict__ slot,
                                         const float* __restrict__ A,
                                         const float* __restrict__ psW,
                                         float* __restrict__ ha,
                                         float* __restrict__ csd, int nper,
                                         int vb, int t) {
    const int w = t >> 6;
    const int lane = t & 63;
    const int g = vb & 31;
    const int chunk = vb >> 5;
    const int i = g * nper + chunk * 4 + w;
    const int ci = cnt[i];
    const float di = rsqrtf((float)ci + 1.0f);
    const int c = min(ci, CAP);
    const float2* __restrict__ hp2 = (const float2*)hp;
    float2 self = hp2[(size_t)i * 64 + lane];
    float accx = self.x * di * di, accy = self.y * di * di;
    int idx = 0;
    float dv = 0.0f;
    if (lane < c) {
        idx = slot[i * CAP + lane];
        dv = rsqrtf((float)cnt[idx] + 1.0f);
    }
    int j = 0;
    for (; j + 3 < c; j += 4) {
        int s0 = __shfl(idx, j, 64);
        int s1 = __shfl(idx, j + 1, 64);
        int s2 = __shfl(idx, j + 2, 64);
        int s3 = __shfl(idx, j + 3, 64);
        float c0 = __shfl(dv, j, 64) * di;
        float c1 = __shfl(dv, j + 1, 64) * di;
        float c2 = __shfl(dv, j + 2, 64) * di;
        float c3 = __shfl(dv, j + 3, 64) * di;
        float2 v0 = hp2[(size_t)s0 * 64 + lane];
        float2 v1 = hp2[(size_t)s1 * 64 + lane];
        float2 v2 = hp2[(size_t)s2 * 64 + lane];
        float2 v3 = hp2[(size_t)s3 * 64 + lane];
        accx = fmaf(v0.x, c0, accx); accy = fmaf(v0.y, c0, accy);
        accx = fmaf(v1.x, c1, accx); accy = fmaf(v1.y, c1, accy);
        accx = fmaf(v2.x, c2, accx); accy = fmaf(v2.y, c2, accy);
        accx = fmaf(v3.x, c3, accx); accy = fmaf(v3.y, c3, accy);
    }
    for (; j < c; j++) {
        int s = __shfl(idx, j, 64);
        float co = __shfl(dv, j, 64) * di;
        float2 v = hp2[(size_t)s * 64 + lane];
        accx = fmaf(v.x, co, accx); accy = fmaf(v.y, co, accy);
    }
    float2 bb = ((const float2*)b)[lane];
    float2 o;
    o.x = fmaxf(accx + bb.x, 0.0f);
    o.y = fmaxf(accy + bb.y, 0.0f);
    ((float2*)ha)[(size_t)i * 64 + lane] = o;
    float2 Av = ((const float2*)A)[lane];
    float2 Pv = ((const float2*)psW)[lane];
    float a = o.x * Av.x + o.y * Av.y;
    float p = o.x * Pv.x + o.y * Pv.y;
#pragma unroll
    for (int d = 8; d > 0; d >>= 1) {
        a += __shfl_down(a, d, 16);
        p += __shfl_down(p, d, 16);
    }
    float part = a * p;                  // heads at lanes 0,16,32,48
    part += __shfl_down(part, 16, 64);
    part += __shfl_down(part, 32, 64);
    if (lane == 0) csd[i] = part * di;   // pre-scaled by dinv[i]
}

// ---------------------------------------------------------------------------
// WIDE score: wave per node, lanes = neighbors; one gather latency + reduce.
// ---------------------------------------------------------------------------
__device__ __forceinline__ void score_node(const float* __restrict__ csd,
                                           const int* __restrict__ cnt,
                                           const int* __restrict__ slot,
                                           const float* __restrict__ psb,
                                           float* __restrict__ scout, int nper,
                                           int vb, int t) {
    const int w = t >> 6;
    const int lane = t & 63;
    const int g = vb & 31;
    const int chunk = vb >> 5;
    const int i = g * nper + chunk * 4 + w;
    const int ci = cnt[i];
    const int c = min(ci, CAP);
    float v = 0.0f;
    if (lane < c) v = csd[slot[(size_t)i * CAP + lane]];
#pragma unroll
    for (int d = 32; d > 0; d >>= 1) v += __shfl_xor(v, d, 64);
    if (lane == 0)
        scout[i] = rsqrtf((float)ci + 1.0f) * (v + csd[i]) + psb[0];
}

// ---------------------------------------------------------------------------
// Per-graph top-k SET via 4-pass radix select (wave digit pre-merge).
// ---------------------------------------------------------------------------
__device__ __forceinline__ void topk_body(SMem& sm, const float* __restrict__ scin,
                                          int nper, int k, int* __restrict__ nmap,
                                          int* __restrict__ perm,
                                          float* __restrict__ mult, int g, int t) {
    __syncthreads();
    const int w = t >> 6, l = t & 63;
    const int gnb = g * nper;
    for (int i = t; i < nper; i += 256) {
        float v = scin[gnb + i];
        sm.tk.sc[i] = v;
        sm.tk.ukey[i] = enc_f(v);
    }
    if (t == 0) { sm.tk.sel[0] = 0u; sm.tk.sel[1] = (unsigned)k; }
    __syncthreads();
    for (int shift = 24; shift >= 0; shift -= 8) {
        sm.tk.hist[t] = 0u;
        __syncthreads();
        const unsigned prefix = sm.tk.sel[0];
        const unsigned need = sm.tk.sel[1];
        for (int i = t; i < nper; i += 256) {
            unsigned u = sm.tk.ukey[i];
            bool inp = (shift == 24) || ((u >> (shift + 8)) == (prefix >> (shift + 8)));
            int dig = inp ? (int)((u >> shift) & 255u) : -1;
            int cv = inp ? 1 : 0;
#pragma unroll
            for (int d = 1; d < 64; d <<= 1) {
                int od = __shfl_xor(dig, d, 64);
                int oc = __shfl_xor(cv, d, 64);
                if (od == dig) cv = ((l & d) == 0) ? (cv + oc) : 0;
            }
            if (dig >= 0 && cv > 0) atomicAdd(&sm.tk.hist[dig], (unsigned)cv);
        }
        __syncthreads();
        const unsigned h = sm.tk.hist[t];
        unsigned s = h;
#pragma unroll
        for (int off = 1; off < 64; off <<= 1) {
            unsigned v = __shfl_down(s, off, 64);
            if (l + off < 64) s += v;
        }
        if (l == 0) sm.tk.wtot[w] = s;
        __syncthreads();
        unsigned add = 0;
        for (int ww = w + 1; ww < 4; ww++) add += sm.tk.wtot[ww];
        const unsigned sfx = s + add;   // #keys with digit >= t (within prefix)
        const unsigned gtr = sfx - h;   // #keys with digit >  t
        if (sfx >= need && gtr < need) {  // exactly one thread
            sm.tk.sel[0] = prefix | ((unsigned)t << shift);
            sm.tk.sel[1] = need - gtr;
        }
        __syncthreads();
    }
    const unsigned T = sm.tk.sel[0];
    const int need = (int)sm.tk.sel[1];
    if (t == 0) { sm.tk.ctr[0] = 0; sm.tk.ctr[1] = k - need; }
    __syncthreads();
    for (int i = t; i < nper; i += 256) {
        unsigned u = sm.tk.ukey[i];
        int node = gnb + i;
        int newid = -1;
        if (u > T) {
            newid = g * k + atomicAdd(&sm.tk.ctr[0], 1);
        } else if (u == T) {
            int slot2 = atomicAdd(&sm.tk.ctr[1], 1);
            if (slot2 < k) newid = g * k + slot2;
        }
        nmap[node] = newid;
        if (newid >= 0) {
            perm[newid] = node;
            mult[newid] = tanhf(sm.tk.sc[i]);
        }
    }
}

// ---------------------------------------------------------------------------
// Final MLP + log_softmax (one virtual block per graph, 256 threads).
// ---------------------------------------------------------------------------
__device__ __forceinline__ void final_body(SMem& sm, const unsigned* __restrict__ rmax,
                                           const float* __restrict__ rsum,
                                           const float* __restrict__ l1W,
                                           const float* __restrict__ l1b,
                                           const float* __restrict__ l2W,
                                           const float* __restrict__ l2b,
                                           const float* __restrict__ l3W,
                                           const float* __restrict__ l3b,
                                           float* __restrict__ out, int g, int t) {
    __syncthreads();
    if (t < 128) {
        sm.mlp.sz[t] = dec_f(rmax[g * FDIM + t]) + dec_f(rmax[RSEC + g * FDIM + t]) +
                       dec_f(rmax[2 * RSEC + g * FDIM + t]);
    } else {
        int f = t - 128;
        sm.mlp.sz[t] = rsum[g * FDIM + f] / (float)K1 +
                       rsum[RSEC + g * FDIM + f] / (float)K2 +
                       rsum[2 * RSEC + g * FDIM + f] / (float)K3;
    }
    __syncthreads();
    if (t < 128) {
        float acc = l1b[t];
        for (int i = 0; i < 256; i++) acc = fmaf(sm.mlp.sz[i], l1W[i * 128 + t], acc);
        sm.mlp.s1[t] = fmaxf(acc, 0.0f);
    }
    __syncthreads();
    if (t < 64) {
        float a2 = l2b[t];
        for (int i = 0; i < 128; i++) a2 = fmaf(sm.mlp.s1[i], l2W[i * 64 + t], a2);
        sm.mlp.s2[t] = fmaxf(a2, 0.0f);
    }
    __syncthreads();
    if (t < 10) {
        float a3 = l3b[t];
        for (int i = 0; i < 64; i++) a3 = fmaf(sm.mlp.s2[i], l3W[i * 10 + t], a3);
        sm.mlp.s3[t] = a3;
    }
    __syncthreads();
    if (t == 0) {
        float m = -1e30f;
        for (int c = 0; c < 10; c++) m = fmaxf(m, sm.mlp.s3[c]);
        float sum = 0.0f;
        for (int c = 0; c < 10; c++) sum += expf(sm.mlp.s3[c] - m);
        sm.mlp.red[0] = m;
        sm.mlp.red[1] = logf(sum);
    }
    __syncthreads();
    if (t < 10) out[g * 10 + t] = sm.mlp.s3[t] - sm.mlp.red[0] - sm.mlp.red[1];
}

// ---------------------------------------------------------------------------
// Parameter block (single by-value kernel arg).
// ---------------------------------------------------------------------------
struct MPar {
    const float *x; const int *src0, *dst0;
    const float *W1, *b1, *A1, *ps1W, *ps1b;
    const float *W2, *b2, *A2, *ps2W, *ps2b;
    const float *W3, *b3, *A3, *ps3W, *ps3b;
    const float *l1W, *l1b, *l2W, *l2b, *l3W, *l3b;
    float *out;
    float *hproj, *hact;
    int *cntA, *cntB, *cntC, *slotA, *slotB, *slotC;
    float *cs, *scb;
    int *nmapA, *nmapB, *nmapC, *perm;
    float *mult;
    unsigned *rmax; float *rsum;
    unsigned *bars;   // 14 x {count, flag} pairs (pre-zeroed)
};

// ---------------------------------------------------------------------------
// Persistent mega-kernel: the whole 3-stage pipeline, 14 grid barriers.
// Phase widths are multiples of 32 -> vb&31 == blk&31 (graph->XCD locality).
// ---------------------------------------------------------------------------
__global__ __launch_bounds__(256, 4) void mega(MPar p) {
    __shared__ SMem sm;
    const int blk = blockIdx.x, t = threadIdx.x;

    // P0: zero cntA + readout accumulators
    {
        int i = blk * 256 + t;
        if (i < N0) p.cntA[i] = 0;
        if (i < 3 * RSEC) { p.rmax[i] = 0u; p.rsum[i] = 0.0f; }
    }
    gbar(p.bars + 0, t);

    // P1: edge binning (2048 vb, graph-swizzled) + proj1 (1024 vb)
    for (int vb = blk; vb < EBLK + N0 / 32; vb += GRID) {
        if (vb < EBLK) {
            int g = vb & 31, ch = vb >> 5;
            int e = g * EPG + ch * 256 + t;
            int s = p.src0[e];
            int d = p.dst0[e];
            int q = atomicAdd(&p.cntA[d], 1);
            if (q < CAP) p.slotA[d * CAP + q] = s;
        } else {
            int tb = vb - EBLK;
            int nb = (tb & 31) * NPER0 + (tb >> 5) * 32;
            proj_tile(sm, t, nb, p.W1, p.x, nullptr, nullptr, p.hproj);
        }
    }
    gbar(p.bars + 2, t);

    // P2: agg1
    for (int vb = blk; vb < N0 / 4; vb += GRID)
        agg_node(p.hproj, p.b1, p.cntA, p.slotA, p.A1, p.ps1W, p.hact, p.cs, NPER0, vb, t);
    gbar(p.bars + 4, t);

    // P3: score1
    for (int vb = blk; vb < N0 / 4; vb += GRID)
        score_node(p.cs, p.cntA, p.slotA, p.ps1b, p.scb, NPER0, vb, t);
    gbar(p.bars + 6, t);

    // P4: topk1
    for (int vb = blk; vb < BGR; vb += GRID)
        topk_body(sm, p.scb, NPER0, K1, p.nmapA, p.perm, p.mult, vb, t);
    gbar(p.bars + 8, t);

    // P5: comp2 (4096) + proj2 (512) + pool1 (2048)
    for (int vb = blk; vb < N1 / 4 + N1 / 32 + BGR * K1 / 8; vb += GRID) {
        if (vb < N1 / 4) {
            comp_node(p.cntA, p.slotA, p.nmapA, p.cntB, p.slotB, p.perm, K1, vb, t);
        } else if (vb < N1 / 4 + N1 / 32) {
            int tb = vb - N1 / 4;
            int nb = (tb & 31) * K1 + (tb >> 5) * 32;
            proj_tile(sm, t, nb, p.W2, p.hact, p.perm, p.mult, p.hproj);
        } else {
            pool8(sm, p.hact, p.perm, p.mult, K1, vb - N1 / 4 - N1 / 32,
                  p.rmax, p.rsum, t);
        }
    }
    gbar(p.bars + 10, t);

    // P6: agg2
    for (int vb = blk; vb < N1 / 4; vb += GRID)
        agg_node(p.hproj, p.b2, p.cntB, p.slotB, p.A2, p.ps2W, p.hact, p.cs, K1, vb, t);
    gbar(p.bars + 12, t);

    // P7: score2
    for (int vb = blk; vb < N1 / 4; vb += GRID)
        score_node(p.cs, p.cntB, p.slotB, p.ps2b, p.scb, K1, vb, t);
    gbar(p.bars + 14, t);

    // P8: topk2
    for (int vb = blk; vb < BGR; vb += GRID)
        topk_body(sm, p.scb, K1, K2, p.nmapB, p.perm, p.mult, vb, t);
    gbar(p.bars + 16, t);

    // P9: comp3 (2048) + proj3 (256) + pool2 (1024)
    for (int vb = blk; vb < N2 / 4 + N2 / 32 + BGR * K2 / 8; vb += GRID) {
        if (vb < N2 / 4) {
            comp_node(p.cntB, p.slotB, p.nmapB, p.cntC, p.slotC, p.perm, K2, vb, t);
        } else if (vb < N2 / 4 + N2 / 32) {
            int tb = vb - N2 / 4;
            int nb = (tb & 31) * K2 + (tb >> 5) * 32;
            proj_tile(sm, t, nb, p.W3, p.hact, p.perm, p.mult, p.hproj);
        } else {
            pool8(sm, p.hact, p.perm, p.mult, K2, vb - N2 / 4 - N2 / 32,
                  p.rmax + RSEC, p.rsum + RSEC, t);
        }
    }
    gbar(p.bars + 18, t);

    // P10: agg3
    for (int vb = blk; vb < N2 / 4; vb += GRID)
        agg_node(p.hproj, p.b3, p.cntC, p.slotC, p.A3, p.ps3W, p.hact, p.cs, K2, vb, t);
    gbar(p.bars + 20, t);

    // P11: score3
    for (int vb = blk; vb < N2 / 4; vb += GRID)
        score_node(p.cs, p.cntC, p.slotC, p.ps3b, p.scb, K2, vb, t);
    gbar(p.bars + 22, t);

    // P12: topk3
    for (int vb = blk; vb < BGR; vb += GRID)
        topk_body(sm, p.scb, K2, K3, p.nmapC, p.perm, p.mult, vb, t);
    gbar(p.bars + 24, t);

    // P13: pool3 (512 vb)
    for (int vb = blk; vb < BGR * K3 / 8; vb += GRID)
        pool8(sm, p.hact, p.perm, p.mult, K3, vb, p.rmax + 2 * RSEC,
              p.rsum + 2 * RSEC, t);
    gbar(p.bars + 26, t);

    // P14: final MLP (32 vb)
    for (int vb = blk; vb < BGR; vb += GRID)
        final_body(sm, p.rmax, p.rsum, p.l1W, p.l1b, p.l2W, p.l2b, p.l3W, p.l3b,
                   p.out, vb, t);
}

// ---------------------------------------------------------------------------
extern "C" void kernel_launch(void* const* d_in, const int* in_sizes, int n_in,
                              void* d_out, int out_size, void* d_ws, size_t ws_size,
                              hipStream_t stream) {
    char* ws = (char*)d_ws;
    size_t o = 0;
    auto alloc = [&](size_t bytes) -> void* {
        void* p = ws + o;
        o += (bytes + 255) & ~(size_t)255;
        return p;
    };
    MPar P;
    P.x    = (const float*)d_in[0];
    P.src0 = (const int*)d_in[1];
    P.dst0 = (const int*)d_in[2];
    P.W1 = (const float*)d_in[3];  P.b1 = (const float*)d_in[4];
    P.A1 = (const float*)d_in[5];  P.ps1W = (const float*)d_in[6];
    P.ps1b = (const float*)d_in[7];
    P.W2 = (const float*)d_in[8];  P.b2 = (const float*)d_in[9];
    P.A2 = (const float*)d_in[10]; P.ps2W = (const float*)d_in[11];
    P.ps2b = (const float*)d_in[12];
    P.W3 = (const float*)d_in[13]; P.b3 = (const float*)d_in[14];
    P.A3 = (const float*)d_in[15]; P.ps3W = (const float*)d_in[16];
    P.ps3b = (const float*)d_in[17];
    P.l1W = (const float*)d_in[18]; P.l1b = (const float*)d_in[19];
    P.l2W = (const float*)d_in[20]; P.l2b = (const float*)d_in[21];
    P.l3W = (const float*)d_in[22]; P.l3b = (const float*)d_in[23];
    P.out = (float*)d_out;

    P.hproj = (float*)alloc((size_t)N0 * FDIM * 4);
    P.hact  = (float*)alloc((size_t)N0 * FDIM * 4);
    P.cntA  = (int*)alloc(N0 * 4);
    P.cntB  = (int*)alloc(N1 * 4);
    P.cntC  = (int*)alloc(N2 * 4);
    P.slotA = (int*)alloc((size_t)N0 * CAP * 4);
    P.slotB = (int*)alloc((size_t)N1 * CAP * 4);
    P.slotC = (int*)alloc((size_t)N2 * CAP * 4);
    P.cs    = (float*)alloc(N0 * 4);
    P.scb   = (float*)alloc(N0 * 4);
    P.nmapA = (int*)alloc(N0 * 4);
    P.nmapB = (int*)alloc(N1 * 4);
    P.nmapC = (int*)alloc(N2 * 4);
    P.perm  = (int*)alloc(N1 * 4);
    P.mult  = (float*)alloc(N1 * 4);
    P.rmax  = (unsigned*)alloc(3 * RSEC * 4);
    P.rsum  = (float*)alloc(3 * RSEC * 4);
    P.bars  = (unsigned*)alloc(128);

    hipMemsetAsync(P.bars, 0, 128, stream);
    mega<<<GRID, 256, 0, stream>>>(P);

    (void)in_sizes; (void)n_in; (void)out_size; (void)ws_size;
}

// Round 5
// 755.886 us; speedup vs baseline: 3.5520x; 1.7465x over previous
//
#include <hip/hip_runtime.h>
#include <math.h>

#define BGR 32
#define NPER0 1024
#define N0 (BGR * NPER0)
#define FDIM 128
#define EDG 524288
#define EPG (EDG / BGR)    // 16384 edges per graph (contiguous by construction)
#define K1 512
#define K2 256
#define K3 128
#define N1 (BGR * K1)
#define N2 (BGR * K2)
#define SXP 36             // sxT row pad (floats): 16B-aligned b128 reads
#define CAP 64             // slots per node (Poisson(16); P(deg>64) ~ 1e-18)
#define TPB 1024           // one workgroup per graph; 16 waves

// Order-preserving float->uint encoding (radix keys only).
__device__ __forceinline__ unsigned enc_f(float v) {
    unsigned u = __float_as_uint(v);
    return (u & 0x80000000u) ? ~u : (u | 0x80000000u);
}

// ---------------------------------------------------------------------------
// Persistent per-graph LDS state (lives across all phases).
// ---------------------------------------------------------------------------
struct Sh {
    int cnt1[NPER0];           // stage-1 degrees
    int cnt2[K1];              // stage-2 degrees (compacted)
    int cnt3[K2];              // stage-3 degrees
    int nmap[NPER0];           // old-local -> new-local (or -1)
    int perm[K1];              // new-local -> old-local
    float mult[K1];            // tanh(score) of kept nodes
    float csd[NPER0];          // per-node attention partial (pre-scaled by dinv)
    float rmax[3][FDIM];       // per-stage pooled max
    float rsum[3][FDIM];       // per-stage pooled sum
};

// Phase-overlay union.
union Ov {
    struct { float W[4096]; float xT[4][128 * SXP]; } proj;        // 90112 B
    struct { float sc[NPER0]; unsigned ukey[NPER0]; unsigned hist[256];
             unsigned wtot[4]; unsigned sel[2]; int ctr[2]; } tk;  // 9248 B
    struct { float pm[8][FDIM]; float ps[8][FDIM]; } pool;         // 8 KB
    struct { float sz[256]; float s1[FDIM]; float s2[64]; float s3[16];
             float red[2]; } mlp;
};

// ---------------------------------------------------------------------------
// Register-tiled projection compute: 32 nodes x 128 feats per tile;
// tid=(feature-quad, node-quad); 4x4 outer product, 2 ds_read_b128/k-step.
// hp is the GRAPH slab base; nb is the local node base of this tile.
// ---------------------------------------------------------------------------
__device__ __forceinline__ void proj_compute(float* __restrict__ hp, int nb, int tid,
                                             const float* __restrict__ sW,
                                             const float* __restrict__ sxT) {
    const int fg = tid >> 3, ng = tid & 7, h = fg >> 3;
    const float* ap = sxT + h * 32 * SXP + ng * 4;
    const float* bp = sW + h * 1024 + (fg & 7) * 4;
    float4 acc0 = {0.f, 0.f, 0.f, 0.f}, acc1 = acc0, acc2 = acc0, acc3 = acc0;
#pragma unroll
    for (int k = 0; k < 32; k++) {
        float4 a = *(const float4*)(ap + k * SXP);
        float4 b = *(const float4*)(bp + k * 32);
        acc0.x = fmaf(a.x, b.x, acc0.x); acc0.y = fmaf(a.x, b.y, acc0.y);
        acc0.z = fmaf(a.x, b.z, acc0.z); acc0.w = fmaf(a.x, b.w, acc0.w);
        acc1.x = fmaf(a.y, b.x, acc1.x); acc1.y = fmaf(a.y, b.y, acc1.y);
        acc1.z = fmaf(a.y, b.z, acc1.z); acc1.w = fmaf(a.y, b.w, acc1.w);
        acc2.x = fmaf(a.z, b.x, acc2.x); acc2.y = fmaf(a.z, b.y, acc2.y);
        acc2.z = fmaf(a.z, b.z, acc2.z); acc2.w = fmaf(a.z, b.w, acc2.w);
        acc3.x = fmaf(a.w, b.x, acc3.x); acc3.y = fmaf(a.w, b.y, acc3.y);
        acc3.z = fmaf(a.w, b.z, acc3.z); acc3.w = fmaf(a.w, b.w, acc3.w);
    }
    float4* op = (float4*)(hp + (size_t)(nb + ng * 4) * FDIM + fg * 4);
    op[0] = acc0; op[32] = acc1; op[64] = acc2; op[96] = acc3;
}

// ntiles/4 passes of 4 concurrent tiles (thread = [tile(2b) | tid(8b)]).
// W staged once into LDS. permL==nullptr -> direct rows; else perm-gather*mult.
__device__ __forceinline__ void proj_phase(Ov& ov, const float* __restrict__ W,
                                           const float* __restrict__ srcb,
                                           const int* __restrict__ permL,
                                           const float* __restrict__ multL,
                                           float* __restrict__ hp, int ntiles, int t) {
    for (int i = t; i < 4096; i += TPB) ov.proj.W[i] = W[i];
    const int tid = t & 255, tl = t >> 8;
    const int npass = ntiles >> 2;
    for (int ps = 0; ps < npass; ps++) {
        __syncthreads();  // W ready (pass 0) / xT WAR (later passes)
        const int nb = (ps * 4 + tl) * 32;
        float* xT = ov.proj.xT[tl];
        for (int i = tid; i < 4096; i += 256) {
            int node = i >> 7, dim = i & 127;
            int nd = nb + node;
            float v;
            if (permL) v = srcb[(size_t)permL[nd] * FDIM + dim] * multL[nd];
            else       v = srcb[(size_t)nd * FDIM + dim];
            xT[dim * SXP + node] = v;
        }
        __syncthreads();
        proj_compute(hp, nb, tid, ov.proj.W, xT);
    }
    __syncthreads();
}

// ---------------------------------------------------------------------------
// GCN agg + bias + relu + fused attention partial. Wave per node (local ids);
// degrees + neighbor degrees from LDS cnt; csd written to LDS.
// ---------------------------------------------------------------------------
__device__ __forceinline__ void agg_phase(const float* __restrict__ hp,
                                          const float* __restrict__ bia,
                                          const float* __restrict__ A,
                                          const float* __restrict__ psW,
                                          const int* __restrict__ cntL,
                                          const int* __restrict__ slot,
                                          float* __restrict__ ha,
                                          float* __restrict__ csd,
                                          int nper, int w, int lane) {
    const float2 bb = ((const float2*)bia)[lane];
    const float2 Av = ((const float2*)A)[lane];
    const float2 Pv = ((const float2*)psW)[lane];
    const float2* __restrict__ hp2 = (const float2*)hp;
    for (int i = w; i < nper; i += 16) {
        const int ci = cntL[i];
        const float di = rsqrtf((float)ci + 1.0f);
        const int c = min(ci, CAP);
        float2 self = hp2[(size_t)i * 64 + lane];
        float accx = self.x * di * di, accy = self.y * di * di;
        int idx = 0;
        float dv = 0.0f;
        if (lane < c) {
            idx = slot[i * CAP + lane];
            dv = rsqrtf((float)cntL[idx] + 1.0f);
        }
        int j = 0;
        for (; j + 3 < c; j += 4) {
            int s0 = __shfl(idx, j, 64);
            int s1 = __shfl(idx, j + 1, 64);
            int s2 = __shfl(idx, j + 2, 64);
            int s3 = __shfl(idx, j + 3, 64);
            float c0 = __shfl(dv, j, 64) * di;
            float c1 = __shfl(dv, j + 1, 64) * di;
            float c2 = __shfl(dv, j + 2, 64) * di;
            float c3 = __shfl(dv, j + 3, 64) * di;
            float2 v0 = hp2[(size_t)s0 * 64 + lane];
            float2 v1 = hp2[(size_t)s1 * 64 + lane];
            float2 v2 = hp2[(size_t)s2 * 64 + lane];
            float2 v3 = hp2[(size_t)s3 * 64 + lane];
            accx = fmaf(v0.x, c0, accx); accy = fmaf(v0.y, c0, accy);
            accx = fmaf(v1.x, c1, accx); accy = fmaf(v1.y, c1, accy);
            accx = fmaf(v2.x, c2, accx); accy = fmaf(v2.y, c2, accy);
            accx = fmaf(v3.x, c3, accx); accy = fmaf(v3.y, c3, accy);
        }
        for (; j < c; j++) {
            int s = __shfl(idx, j, 64);
            float co = __shfl(dv, j, 64) * di;
            float2 v = hp2[(size_t)s * 64 + lane];
            accx = fmaf(v.x, co, accx); accy = fmaf(v.y, co, accy);
        }
        float2 o;
        o.x = fmaxf(accx + bb.x, 0.0f);
        o.y = fmaxf(accy + bb.y, 0.0f);
        ((float2*)ha)[(size_t)i * 64 + lane] = o;
        float a = o.x * Av.x + o.y * Av.y;
        float p = o.x * Pv.x + o.y * Pv.y;
#pragma unroll
        for (int d = 8; d > 0; d >>= 1) {
            a += __shfl_down(a, d, 16);
            p += __shfl_down(p, d, 16);
        }
        float part = a * p;                    // heads at lanes 0,16,32,48
        part += __shfl_down(part, 16, 64);
        part += __shfl_down(part, 32, 64);
        if (lane == 0) csd[i] = part * di;     // pre-scaled by dinv[i]
    }
}

// ---------------------------------------------------------------------------
// Top-k with INLINE score (thread per node; csd + cnt in LDS, slot row global).
// 4-pass radix select over LDS keys; writes nmap/perm/mult (all LDS).
// ---------------------------------------------------------------------------
__device__ __forceinline__ void topk_phase(Sh& sh, Ov& ov,
                                           const int* __restrict__ slot,
                                           const int* __restrict__ cntL,
                                           float pb, int nper, int k, int t) {
    if (t < nper) {
        int ci = cntL[t];
        int c = min(ci, CAP);
        const int* srow = slot + t * CAP;
        float v = 0.0f;
        for (int j = 0; j < c; j++) v += sh.csd[srow[j]];
        float s = rsqrtf((float)ci + 1.0f) * (v + sh.csd[t]) + pb;
        ov.tk.sc[t] = s;
        ov.tk.ukey[t] = enc_f(s);
    }
    if (t == 0) { ov.tk.sel[0] = 0u; ov.tk.sel[1] = (unsigned)k; }
    __syncthreads();
    const int w4 = t >> 6, l = t & 63;
    for (int shift = 24; shift >= 0; shift -= 8) {
        if (t < 256) ov.tk.hist[t] = 0u;
        __syncthreads();
        const unsigned prefix = ov.tk.sel[0];
        const unsigned need = ov.tk.sel[1];
        {   // build histogram with wave equal-digit pre-merge
            unsigned u = (t < nper) ? ov.tk.ukey[t] : 0u;
            bool inp = (t < nper) &&
                       ((shift == 24) || ((u >> (shift + 8)) == (prefix >> (shift + 8))));
            int dig = inp ? (int)((u >> shift) & 255u) : -1;
            int cv = inp ? 1 : 0;
#pragma unroll
            for (int d = 1; d < 64; d <<= 1) {
                int od = __shfl_xor(dig, d, 64);
                int oc = __shfl_xor(cv, d, 64);
                if (od == dig) cv = ((l & d) == 0) ? (cv + oc) : 0;
            }
            if (dig >= 0 && cv > 0) atomicAdd(&ov.tk.hist[dig], (unsigned)cv);
        }
        __syncthreads();
        unsigned h = 0, s = 0;
        if (t < 256) {
            h = ov.tk.hist[t];
            s = h;
#pragma unroll
            for (int off = 1; off < 64; off <<= 1) {
                unsigned v2 = __shfl_down(s, off, 64);
                if (l + off < 64) s += v2;
            }
            if (l == 0) ov.tk.wtot[w4] = s;
        }
        __syncthreads();
        if (t < 256) {
            unsigned add = 0;
            for (int ww = w4 + 1; ww < 4; ww++) add += ov.tk.wtot[ww];
            const unsigned sfx = s + add;   // #keys with digit >= t (within prefix)
            const unsigned gtr = sfx - h;   // #keys with digit >  t
            if (sfx >= need && gtr < need) {  // exactly one thread
                ov.tk.sel[0] = prefix | ((unsigned)t << shift);
                ov.tk.sel[1] = need - gtr;
            }
        }
        __syncthreads();
    }
    const unsigned T = ov.tk.sel[0];
    const int need2 = (int)ov.tk.sel[1];
    if (t == 0) { ov.tk.ctr[0] = 0; ov.tk.ctr[1] = k - need2; }
    __syncthreads();
    if (t < nper) {
        unsigned u = ov.tk.ukey[t];
        int newid = -1;
        if (u > T) {
            newid = atomicAdd(&ov.tk.ctr[0], 1);
        } else if (u == T) {
            int s2 = atomicAdd(&ov.tk.ctr[1], 1);
            if (s2 < k) newid = s2;
        }
        sh.nmap[t] = newid;
        if (newid >= 0) {
            sh.perm[newid] = t;
            sh.mult[newid] = tanhf(ov.tk.sc[t]);
        }
    }
    __syncthreads();
}

// ---------------------------------------------------------------------------
// Slot compaction (wave per kept node; nmap/perm/cnt in LDS; no atomics).
// ---------------------------------------------------------------------------
__device__ __forceinline__ void comp_phase(Sh& sh, const int* __restrict__ cntPrevL,
                                           const int* __restrict__ slotPrev,
                                           int* __restrict__ cntNextL,
                                           int* __restrict__ slotNext,
                                           int knext, int w, int lane) {
    for (int b = w; b < knext; b += 16) {
        int old = sh.perm[b];
        int c = min(cntPrevL[old], CAP);
        int a = -1;
        if (lane < c) a = sh.nmap[slotPrev[old * CAP + lane]];
        unsigned long long mk = __ballot(a >= 0);
        if (a >= 0) {
            int pos = __popcll(mk & ((1ull << lane) - 1ull));
            slotNext[b * CAP + pos] = a;
        }
        if (lane == 0) cntNextL[b] = __popcll(mk);
    }
}

// ---------------------------------------------------------------------------
// Pooling readout (block-local, no atomics): thread=(f, chunk of 8).
// ---------------------------------------------------------------------------
__device__ __forceinline__ void pool_phase(Sh& sh, Ov& ov, const float* __restrict__ ha,
                                           int k, int stage, int t) {
    const int f = t & 127, ch = t >> 7;  // 8 chunks
    float vmax = -1e30f, vsum = 0.0f;
    for (int j = ch; j < k; j += 8) {
        int old = sh.perm[j];
        float m = sh.mult[j];
        float v = ha[(size_t)old * FDIM + f] * m;
        vmax = fmaxf(vmax, v);
        vsum += v;
    }
    ov.pool.pm[ch][f] = vmax;
    ov.pool.ps[ch][f] = vsum;
    __syncthreads();
    if (t < FDIM) {
        float M = ov.pool.pm[0][t], S = ov.pool.ps[0][t];
#pragma unroll
        for (int c2 = 1; c2 < 8; c2++) {
            M = fmaxf(M, ov.pool.pm[c2][t]);
            S += ov.pool.ps[c2][t];
        }
        sh.rmax[stage][t] = M;
        sh.rsum[stage][t] = S;
    }
    __syncthreads();
}

// ---------------------------------------------------------------------------
struct MPar {
    const float *x; const int *src0, *dst0;
    const float *W1, *b1, *A1, *ps1W, *ps1b;
    const float *W2, *b2, *A2, *ps2W, *ps2b;
    const float *W3, *b3, *A3, *ps3W, *ps3b;
    const float *l1W, *l1b, *l2W, *l2b, *l3W, *l3b;
    float *out;
    float *hp1, *ha1, *hp2, *ha2, *hp3, *ha3;     // per-stage slabs (no aliasing)
    int *slotA, *slotB, *slotC;
};

// ---------------------------------------------------------------------------
// One workgroup per graph: entire pipeline, __syncthreads-only phase sync.
// No global atomics, no fences, no cross-block communication at all.
// ---------------------------------------------------------------------------
__global__ __launch_bounds__(1024, 4) void graph_pipe(MPar p) {
    __shared__ Sh sh;
    __shared__ Ov ov;
    const int g = blockIdx.x, t = threadIdx.x;
    const int w = t >> 6, lane = t & 63;

    float* hp1 = p.hp1 + (size_t)g * NPER0 * FDIM;
    float* ha1 = p.ha1 + (size_t)g * NPER0 * FDIM;
    float* hp2 = p.hp2 + (size_t)g * K1 * FDIM;
    float* ha2 = p.ha2 + (size_t)g * K1 * FDIM;
    float* hp3 = p.hp3 + (size_t)g * K2 * FDIM;
    float* ha3 = p.ha3 + (size_t)g * K2 * FDIM;
    int* slotA = p.slotA + (size_t)g * NPER0 * CAP;
    int* slotB = p.slotB + (size_t)g * K1 * CAP;
    int* slotC = p.slotC + (size_t)g * K2 * CAP;

    // P0: zero stage-1 degree counters
    if (t < NPER0) sh.cnt1[t] = 0;
    __syncthreads();

    // P1: edge binning (LDS degree atomics, local ids into global slot slab)
    {
        const int ebase = g * EPG;
#pragma unroll 4
        for (int r = 0; r < EPG / TPB; r++) {
            int e = ebase + r * TPB + t;
            int s = p.src0[e] - g * NPER0;
            int d = p.dst0[e] - g * NPER0;
            int q = atomicAdd(&sh.cnt1[d], 1);
            if (q < CAP) slotA[d * CAP + q] = s;
        }
    }
    __syncthreads();

    // P2: proj1 (x -> hp1), 32 tiles
    proj_phase(ov, p.W1, p.x + (size_t)g * NPER0 * FDIM, nullptr, nullptr, hp1, 32, t);

    // P3: agg1 (hp1 -> ha1, csd)
    agg_phase(hp1, p.b1, p.A1, p.ps1W, sh.cnt1, slotA, ha1, sh.csd, NPER0, w, lane);
    __syncthreads();

    // P4: topk1 (inline score) -> nmap/perm/mult
    topk_phase(sh, ov, slotA, sh.cnt1, p.ps1b[0], NPER0, K1, t);

    // P5: comp2 (slotA -> slotB, cnt2)
    comp_phase(sh, sh.cnt1, slotA, sh.cnt2, slotB, K1, w, lane);
    __syncthreads();

    // P6: pool1 (ha1 via perm -> rmax/rsum[0])
    pool_phase(sh, ov, ha1, K1, 0, t);

    // P7: proj2 (perm-gathered ha1 -> hp2), 16 tiles
    proj_phase(ov, p.W2, ha1, sh.perm, sh.mult, hp2, 16, t);

    // P8: agg2
    agg_phase(hp2, p.b2, p.A2, p.ps2W, sh.cnt2, slotB, ha2, sh.csd, K1, w, lane);
    __syncthreads();

    // P9: topk2
    topk_phase(sh, ov, slotB, sh.cnt2, p.ps2b[0], K1, K2, t);

    // P10: comp3
    comp_phase(sh, sh.cnt2, slotB, sh.cnt3, slotC, K2, w, lane);
    __syncthreads();

    // P11: pool2 (ha2 via perm -> rmax/rsum[1])
    pool_phase(sh, ov, ha2, K2, 1, t);

    // P12: proj3 (perm-gathered ha2 -> hp3), 8 tiles
    proj_phase(ov, p.W3, ha2, sh.perm, sh.mult, hp3, 8, t);

    // P13: agg3
    agg_phase(hp3, p.b3, p.A3, p.ps3W, sh.cnt3, slotC, ha3, sh.csd, K2, w, lane);
    __syncthreads();

    // P14: topk3
    topk_phase(sh, ov, slotC, sh.cnt3, p.ps3b[0], K2, K3, t);

    // P15: pool3 (ha3 via perm -> rmax/rsum[2])
    pool_phase(sh, ov, ha3, K3, 2, t);

    // P16: final MLP + log_softmax
    if (t < FDIM) {
        ov.mlp.sz[t] = sh.rmax[0][t] + sh.rmax[1][t] + sh.rmax[2][t];
    } else if (t < 256) {
        int f = t - 128;
        ov.mlp.sz[t] = sh.rsum[0][f] / (float)K1 + sh.rsum[1][f] / (float)K2 +
                       sh.rsum[2][f] / (float)K3;
    }
    __syncthreads();
    if (t < 128) {
        float acc = p.l1b[t];
        for (int i = 0; i < 256; i++) acc = fmaf(ov.mlp.sz[i], p.l1W[i * 128 + t], acc);
        ov.mlp.s1[t] = fmaxf(acc, 0.0f);
    }
    __syncthreads();
    if (t < 64) {
        float a2 = p.l2b[t];
        for (int i = 0; i < 128; i++) a2 = fmaf(ov.mlp.s1[i], p.l2W[i * 64 + t], a2);
        ov.mlp.s2[t] = fmaxf(a2, 0.0f);
    }
    __syncthreads();
    if (t < 10) {
        float a3 = p.l3b[t];
        for (int i = 0; i < 64; i++) a3 = fmaf(ov.mlp.s2[i], p.l3W[i * 10 + t], a3);
        ov.mlp.s3[t] = a3;
    }
    __syncthreads();
    if (t == 0) {
        float m = -1e30f;
        for (int c = 0; c < 10; c++) m = fmaxf(m, ov.mlp.s3[c]);
        float sum = 0.0f;
        for (int c = 0; c < 10; c++) sum += expf(ov.mlp.s3[c] - m);
        ov.mlp.red[0] = m;
        ov.mlp.red[1] = logf(sum);
    }
    __syncthreads();
    if (t < 10) p.out[g * 10 + t] = ov.mlp.s3[t] - ov.mlp.red[0] - ov.mlp.red[1];
}

// ---------------------------------------------------------------------------
extern "C" void kernel_launch(void* const* d_in, const int* in_sizes, int n_in,
                              void* d_out, int out_size, void* d_ws, size_t ws_size,
                              hipStream_t stream) {
    char* ws = (char*)d_ws;
    size_t o = 0;
    auto alloc = [&](size_t bytes) -> void* {
        void* p = ws + o;
        o += (bytes + 255) & ~(size_t)255;
        return p;
    };
    MPar P;
    P.x    = (const float*)d_in[0];
    P.src0 = (const int*)d_in[1];
    P.dst0 = (const int*)d_in[2];
    P.W1 = (const float*)d_in[3];  P.b1 = (const float*)d_in[4];
    P.A1 = (const float*)d_in[5];  P.ps1W = (const float*)d_in[6];
    P.ps1b = (const float*)d_in[7];
    P.W2 = (const float*)d_in[8];  P.b2 = (const float*)d_in[9];
    P.A2 = (const float*)d_in[10]; P.ps2W = (const float*)d_in[11];
    P.ps2b = (const float*)d_in[12];
    P.W3 = (const float*)d_in[13]; P.b3 = (const float*)d_in[14];
    P.A3 = (const float*)d_in[15]; P.ps3W = (const float*)d_in[16];
    P.ps3b = (const float*)d_in[17];
    P.l1W = (const float*)d_in[18]; P.l1b = (const float*)d_in[19];
    P.l2W = (const float*)d_in[20]; P.l2b = (const float*)d_in[21];
    P.l3W = (const float*)d_in[22]; P.l3b = (const float*)d_in[23];
    P.out = (float*)d_out;

    P.hp1 = (float*)alloc((size_t)N0 * FDIM * 4);
    P.ha1 = (float*)alloc((size_t)N0 * FDIM * 4);
    P.hp2 = (float*)alloc((size_t)N1 * FDIM * 4);
    P.ha2 = (float*)alloc((size_t)N1 * FDIM * 4);
    P.hp3 = (float*)alloc((size_t)N2 * FDIM * 4);
    P.ha3 = (float*)alloc((size_t)N2 * FDIM * 4);
    P.slotA = (int*)alloc((size_t)N0 * CAP * 4);
    P.slotB = (int*)alloc((size_t)N1 * CAP * 4);
    P.slotC = (int*)alloc((size_t)N2 * CAP * 4);

    graph_pipe<<<BGR, TPB, 0, stream>>>(P);

    (void)in_sizes; (void)n_in; (void)out_size; (void)ws_size;
}

// Round 6
// 260.295 us; speedup vs baseline: 10.3148x; 2.9040x over previous
//
#include <hip/hip_runtime.h>
#include <math.h>

#define BGR 32
#define NPER0 1024
#define N0 (BGR * NPER0)
#define FDIM 128
#define EDG 524288
#define EPG (EDG / BGR)   // 16384 edges per graph (contiguous by construction)
#define K1 512
#define K2 256
#define K3 128
#define N1 (BGR * K1)
#define N2 (BGR * K2)
#define SXP 36            // sxT row pad (floats): 16B-aligned b128 reads
#define CAP 64            // slots per node (Poisson(16); P(deg>64) ~ 1e-18)
#define RSEC (BGR * FDIM)

// Order-preserving float<->uint encoding (radix keys + atomicMax readout).
__device__ __forceinline__ unsigned enc_f(float v) {
    unsigned u = __float_as_uint(v);
    return (u & 0x80000000u) ? ~u : (u | 0x80000000u);
}
__device__ __forceinline__ float dec_f(unsigned u) {
    return (u & 0x80000000u) ? __uint_as_float(u ^ 0x80000000u) : __uint_as_float(~u);
}

// ---------------------------------------------------------------------------
// Register-tiled projection compute: 32 nodes x 128 feats per tile;
// thread=(feature-quad, node-quad); 4x4 outer product, 2 ds_read_b128/k-step.
// ---------------------------------------------------------------------------
__device__ __forceinline__ void proj_compute(float* __restrict__ hp, int nb, int t,
                                             const float* __restrict__ sW,
                                             const float* __restrict__ sxT) {
    const int fg = t >> 3, ng = t & 7, h = fg >> 3;
    const float* ap = sxT + h * 32 * SXP + ng * 4;
    const float* bp = sW + h * 1024 + (fg & 7) * 4;
    float4 acc0 = {0.f, 0.f, 0.f, 0.f}, acc1 = acc0, acc2 = acc0, acc3 = acc0;
#pragma unroll
    for (int k = 0; k < 32; k++) {
        float4 a = *(const float4*)(ap + k * SXP);
        float4 b = *(const float4*)(bp + k * 32);
        acc0.x = fmaf(a.x, b.x, acc0.x); acc0.y = fmaf(a.x, b.y, acc0.y);
        acc0.z = fmaf(a.x, b.z, acc0.z); acc0.w = fmaf(a.x, b.w, acc0.w);
        acc1.x = fmaf(a.y, b.x, acc1.x); acc1.y = fmaf(a.y, b.y, acc1.y);
        acc1.z = fmaf(a.y, b.z, acc1.z); acc1.w = fmaf(a.y, b.w, acc1.w);
        acc2.x = fmaf(a.z, b.x, acc2.x); acc2.y = fmaf(a.z, b.y, acc2.y);
        acc2.z = fmaf(a.z, b.z, acc2.z); acc2.w = fmaf(a.z, b.w, acc2.w);
        acc3.x = fmaf(a.w, b.x, acc3.x); acc3.y = fmaf(a.w, b.y, acc3.y);
        acc3.z = fmaf(a.w, b.z, acc3.z); acc3.w = fmaf(a.w, b.w, acc3.w);
    }
    float4* op = (float4*)(hp + (size_t)(nb + ng * 4) * FDIM + fg * 4);
    op[0] = acc0; op[32] = acc1; op[64] = acc2; op[96] = acc3;
}

// ---------------------------------------------------------------------------
// Pooling readout (wide): 8 kept nodes per block, 256 threads=(f,half).
// ---------------------------------------------------------------------------
__device__ __forceinline__ void pool_body(const float* __restrict__ ha,
                                          const int* __restrict__ perm,
                                          const float* __restrict__ mult, int k, int pb,
                                          unsigned* __restrict__ rmax,
                                          float* __restrict__ rsum,
                                          float* __restrict__ smax,
                                          float* __restrict__ ssum) {
    const int t = threadIdx.x;
    const int g = pb & 31;
    const int c = pb >> 5;
    const int f = t & 127, half = t >> 7;
    const int base = g * k + c * 8;
    float vmax = -1e30f, vsum = 0.0f;
#pragma unroll
    for (int j0 = 0; j0 < 4; j0++) {
        int newid = base + half + j0 * 2;
        int old = perm[newid];
        float m = mult[newid];
        float v = ha[(size_t)old * FDIM + f] * m;
        vmax = fmaxf(vmax, v);
        vsum += v;
    }
    if (half) { smax[f] = vmax; ssum[f] = vsum; }
    __syncthreads();
    if (!half) {
        vmax = fmaxf(vmax, smax[f]);
        vsum += ssum[f];
        atomicMax(&rmax[g * FDIM + f], enc_f(vmax));
        atomicAdd(&rsum[g * FDIM + f], vsum);
    }
}

// ---------------------------------------------------------------------------
// K1: [0,BGR) per-graph LDS binning (+zero rmax/rsum) | [BGR,...) proj1 tiles.
// LDS binning: degree counters in LDS (no global atomics), cnt written whole.
// ---------------------------------------------------------------------------
__global__ void bin_proj1(const int* __restrict__ src, const int* __restrict__ dst,
                          int* __restrict__ cnt, int* __restrict__ slot,
                          const float* __restrict__ x, const float* __restrict__ W,
                          float* __restrict__ hp,
                          unsigned* __restrict__ rmax, float* __restrict__ rsum) {
    __shared__ __align__(16) float sW[4096];
    __shared__ __align__(16) float sxT[128 * SXP];
    const int t = threadIdx.x;
    if (blockIdx.x < BGR) {
        const int g = blockIdx.x;
        int* lcnt = (int*)sW;  // 1024 ints, LDS reuse
        for (int i = t; i < NPER0; i += 256) lcnt[i] = 0;
        {   // zero readout accumulators (2 stages x 32 graphs x 128 feats)
            int z = g * 256 + t;  // 32*256 == 2*RSEC exactly
            rmax[z] = 0u;
            rsum[z] = 0.0f;
        }
        __syncthreads();
        const int eb = g * EPG;
        for (int r = 0; r < EPG / 256; r++) {
            int e = eb + r * 256 + t;
            int s = src[e];
            int d = dst[e];
            int p = atomicAdd(&lcnt[d - g * NPER0], 1);
            if (p < CAP) slot[(size_t)d * CAP + p] = s;
        }
        __syncthreads();
        for (int i = t; i < NPER0; i += 256) cnt[g * NPER0 + i] = lcnt[i];
        return;
    }
    const int tb = blockIdx.x - BGR;
    const int nb = (tb & 31) * NPER0 + (tb >> 5) * 32;
    for (int i = t; i < 4096; i += 256) sW[i] = W[i];
    for (int i = t; i < 4096; i += 256) {
        int node = i >> 7, dim = i & 127;
        sxT[dim * SXP + node] = x[(size_t)(nb + node) * FDIM + dim];
    }
    __syncthreads();
    proj_compute(hp, nb, t, sW, sxT);
}

// ---------------------------------------------------------------------------
// Fat kernel (stages 2/3): comp (slot compaction) | proj (perm-gather) | pool.
// ---------------------------------------------------------------------------
__global__ void comp_proj_pool(const int* __restrict__ cnt_prev,
                               const int* __restrict__ slot_prev,
                               const int* __restrict__ nmap,
                               int* __restrict__ cnt_next, int* __restrict__ slot_next,
                               const float* __restrict__ ha, const int* __restrict__ perm,
                               const float* __restrict__ mult, const float* __restrict__ W,
                               float* __restrict__ hp, int ncomp, int ntiles, int kprev,
                               unsigned* __restrict__ rmax, float* __restrict__ rsum) {
    __shared__ __align__(16) float sW[4096];
    __shared__ __align__(16) float sxT[128 * SXP];
    const int t = threadIdx.x;
    if (blockIdx.x < ncomp) {
        const int w = t >> 6, lane = t & 63;
        const int b = (blockIdx.x & 31) * kprev + (blockIdx.x >> 5) * 4 + w;
        const int old = perm[b];
        const int c = min(cnt_prev[old], CAP);
        int a = -1;
        if (lane < c) a = nmap[slot_prev[(size_t)old * CAP + lane]];
        unsigned long long mk = __ballot(a >= 0);
        if (a >= 0) {
            int pos = __popcll(mk & ((1ull << lane) - 1ull));
            slot_next[(size_t)b * CAP + pos] = a;
        }
        if (lane == 0) cnt_next[b] = __popcll(mk);
        return;
    }
    if (blockIdx.x >= ncomp + ntiles) {
        pool_body(ha, perm, mult, kprev, blockIdx.x - (ncomp + ntiles), rmax, rsum,
                  sW, sW + 128);
        return;
    }
    const int tb = blockIdx.x - ncomp;
    const int nb = (tb & 31) * kprev + (tb >> 5) * 32;
    for (int i = t; i < 4096; i += 256) sW[i] = W[i];
    for (int i = t; i < 4096; i += 256) {
        int node = i >> 7, dim = i & 127;
        int newid = nb + node;
        sxT[dim * SXP + node] = ha[(size_t)perm[newid] * FDIM + dim] * mult[newid];
    }
    __syncthreads();
    proj_compute(hp, nb, t, sW, sxT);
}

// ---------------------------------------------------------------------------
// GCN aggregation (gather via slots) + bias + relu + fused attention partial.
// Wave per node; lane = 2 features (float2); shfl-broadcast edge prefetch.
// Writes csd[i] = cs_raw[i] * dinv[i].
// ---------------------------------------------------------------------------
__global__ void agg_kernel(const float* __restrict__ hp, const float* __restrict__ b,
                           const int* __restrict__ cnt, const int* __restrict__ slot,
                           const float* __restrict__ A, const float* __restrict__ psW,
                           float* __restrict__ ha, float* __restrict__ csd, int nper) {
    const int w = threadIdx.x >> 6;
    const int lane = threadIdx.x & 63;
    const int g = blockIdx.x & 31;
    const int chunk = blockIdx.x >> 5;
    const int i = g * nper + chunk * 4 + w;
    const int ci = cnt[i];
    const float di = rsqrtf((float)ci + 1.0f);
    const int c = min(ci, CAP);
    const float2* __restrict__ hp2 = (const float2*)hp;
    float2 self = hp2[(size_t)i * 64 + lane];
    float accx = self.x * di * di, accy = self.y * di * di;
    int idx = 0;
    float dv = 0.0f;
    if (lane < c) {
        idx = slot[i * CAP + lane];
        dv = rsqrtf((float)cnt[idx] + 1.0f);
    }
    int j = 0;
    for (; j + 3 < c; j += 4) {
        int s0 = __shfl(idx, j, 64);
        int s1 = __shfl(idx, j + 1, 64);
        int s2 = __shfl(idx, j + 2, 64);
        int s3 = __shfl(idx, j + 3, 64);
        float c0 = __shfl(dv, j, 64) * di;
        float c1 = __shfl(dv, j + 1, 64) * di;
        float c2 = __shfl(dv, j + 2, 64) * di;
        float c3 = __shfl(dv, j + 3, 64) * di;
        float2 v0 = hp2[(size_t)s0 * 64 + lane];
        float2 v1 = hp2[(size_t)s1 * 64 + lane];
        float2 v2 = hp2[(size_t)s2 * 64 + lane];
        float2 v3 = hp2[(size_t)s3 * 64 + lane];
        accx = fmaf(v0.x, c0, accx); accy = fmaf(v0.y, c0, accy);
        accx = fmaf(v1.x, c1, accx); accy = fmaf(v1.y, c1, accy);
        accx = fmaf(v2.x, c2, accx); accy = fmaf(v2.y, c2, accy);
        accx = fmaf(v3.x, c3, accx); accy = fmaf(v3.y, c3, accy);
    }
    for (; j < c; j++) {
        int s = __shfl(idx, j, 64);
        float co = __shfl(dv, j, 64) * di;
        float2 v = hp2[(size_t)s * 64 + lane];
        accx = fmaf(v.x, co, accx); accy = fmaf(v.y, co, accy);
    }
    float2 bb = ((const float2*)b)[lane];
    float2 o;
    o.x = fmaxf(accx + bb.x, 0.0f);
    o.y = fmaxf(accy + bb.y, 0.0f);
    ((float2*)ha)[(size_t)i * 64 + lane] = o;
    float2 Av = ((const float2*)A)[lane];
    float2 Pv = ((const float2*)psW)[lane];
    float a = o.x * Av.x + o.y * Av.y;
    float p = o.x * Pv.x + o.y * Pv.y;
#pragma unroll
    for (int d = 8; d > 0; d >>= 1) {
        a += __shfl_down(a, d, 16);
        p += __shfl_down(p, d, 16);
    }
    float part = a * p;                  // heads at lanes 0,16,32,48
    part += __shfl_down(part, 16, 64);
    part += __shfl_down(part, 32, 64);
    if (lane == 0) csd[i] = part * di;   // pre-scaled by dinv[i]
}

// ---------------------------------------------------------------------------
// Top-k with INLINE score: 1024 threads, one block per graph. csd staged in
// LDS; each thread scores its node (slot row global, csd lookups LDS), then
// 4-pass radix select with wave equal-digit pre-merge.
// ---------------------------------------------------------------------------
__global__ __launch_bounds__(1024) void topk_kernel(
        const float* __restrict__ csd, const int* __restrict__ cnt,
        const int* __restrict__ slot, const float* __restrict__ psb,
        int nper, int k, int* __restrict__ nmap, int* __restrict__ perm,
        float* __restrict__ mult) {
    __shared__ float cs_l[NPER0];
    __shared__ float sc[NPER0];
    __shared__ unsigned ukey[NPER0];
    __shared__ unsigned hist[256];
    __shared__ unsigned wtot[4];
    __shared__ unsigned sel[2];
    __shared__ int ctr[2];
    const int g = blockIdx.x, t = threadIdx.x;
    const int gnb = g * nper;
    if (t < nper) cs_l[t] = csd[gnb + t];
    if (t == 0) { sel[0] = 0u; sel[1] = (unsigned)k; }
    __syncthreads();
    if (t < nper) {
        int ci = cnt[gnb + t];
        int c = min(ci, CAP);
        const int* srow = slot + (size_t)(gnb + t) * CAP;
        float v = 0.0f;
        for (int j = 0; j < c; j++) v += cs_l[srow[j] - gnb];
        float s = rsqrtf((float)ci + 1.0f) * (v + cs_l[t]) + psb[0];
        sc[t] = s;
        ukey[t] = enc_f(s);
    }
    __syncthreads();
    const int w4 = t >> 6, l = t & 63;
    for (int shift = 24; shift >= 0; shift -= 8) {
        if (t < 256) hist[t] = 0u;
        __syncthreads();
        const unsigned prefix = sel[0];
        const unsigned need = sel[1];
        {   // histogram with wave equal-digit pre-merge
            unsigned u = (t < nper) ? ukey[t] : 0u;
            bool inp = (t < nper) &&
                       ((shift == 24) || ((u >> (shift + 8)) == (prefix >> (shift + 8))));
            int dig = inp ? (int)((u >> shift) & 255u) : -1;
            int cv = inp ? 1 : 0;
#pragma unroll
            for (int d = 1; d < 64; d <<= 1) {
                int od = __shfl_xor(dig, d, 64);
                int oc = __shfl_xor(cv, d, 64);
                if (od == dig) cv = ((l & d) == 0) ? (cv + oc) : 0;
            }
            if (dig >= 0 && cv > 0) atomicAdd(&hist[dig], (unsigned)cv);
        }
        __syncthreads();
        unsigned h = 0, s = 0;
        if (t < 256) {
            h = hist[t];
            s = h;
#pragma unroll
            for (int off = 1; off < 64; off <<= 1) {
                unsigned v2 = __shfl_down(s, off, 64);
                if (l + off < 64) s += v2;
            }
            if (l == 0) wtot[w4] = s;
        }
        __syncthreads();
        if (t < 256) {
            unsigned add = 0;
            for (int ww = w4 + 1; ww < 4; ww++) add += wtot[ww];
            const unsigned sfx = s + add;   // #keys with digit >= t (within prefix)
            const unsigned gtr = sfx - h;   // #keys with digit >  t
            if (sfx >= need && gtr < need) {  // exactly one thread
                sel[0] = prefix | ((unsigned)t << shift);
                sel[1] = need - gtr;
            }
        }
        __syncthreads();
    }
    const unsigned T = sel[0];
    const int need2 = (int)sel[1];
    if (t == 0) { ctr[0] = 0; ctr[1] = k - need2; }
    __syncthreads();
    if (t < nper) {
        unsigned u = ukey[t];
        int newid = -1;
        if (u > T) {
            newid = atomicAdd(&ctr[0], 1);
        } else if (u == T) {
            int s2 = atomicAdd(&ctr[1], 1);
            if (s2 < k) newid = s2;
        }
        nmap[gnb + t] = (newid >= 0) ? g * k + newid : -1;
        if (newid >= 0) {
            perm[g * k + newid] = gnb + t;
            mult[g * k + newid] = tanhf(sc[t]);
        }
    }
}

// ---------------------------------------------------------------------------
// Final: stage-3 pooling (block-local, 1024 threads) + MLP + log_softmax.
// ---------------------------------------------------------------------------
__global__ __launch_bounds__(1024) void pool3_mlp(
        const float* __restrict__ ha, const int* __restrict__ perm,
        const float* __restrict__ mult,
        const unsigned* __restrict__ rmax, const float* __restrict__ rsum,
        const float* __restrict__ l1W, const float* __restrict__ l1b,
        const float* __restrict__ l2W, const float* __restrict__ l2b,
        const float* __restrict__ l3W, const float* __restrict__ l3b,
        float* __restrict__ out) {
    __shared__ float pm[8][FDIM], ps[8][FDIM];
    __shared__ float sz[256], s1[128], s2[64], s3[16], red[2];
    const int g = blockIdx.x, t = threadIdx.x;
    const int f = t & 127, ch = t >> 7;
    float vmax = -1e30f, vsum = 0.0f;
#pragma unroll
    for (int j = 0; j < K3 / 8; j++) {
        int nid = g * K3 + ch + j * 8;
        int old = perm[nid];
        float m = mult[nid];
        float v = ha[(size_t)old * FDIM + f] * m;
        vmax = fmaxf(vmax, v);
        vsum += v;
    }
    pm[ch][f] = vmax;
    ps[ch][f] = vsum;
    __syncthreads();
    if (t < 128) {
        float M = pm[0][t];
#pragma unroll
        for (int c2 = 1; c2 < 8; c2++) M = fmaxf(M, pm[c2][t]);
        sz[t] = dec_f(rmax[g * FDIM + t]) + dec_f(rmax[RSEC + g * FDIM + t]) + M;
    } else if (t < 256) {
        int f2 = t - 128;
        float S = ps[0][f2];
#pragma unroll
        for (int c2 = 1; c2 < 8; c2++) S += ps[c2][f2];
        sz[t] = rsum[g * FDIM + f2] / (float)K1 + rsum[RSEC + g * FDIM + f2] / (float)K2 +
                S / (float)K3;
    }
    __syncthreads();
    if (t < 128) {
        float acc = l1b[t];
        for (int i = 0; i < 256; i++) acc = fmaf(sz[i], l1W[i * 128 + t], acc);
        s1[t] = fmaxf(acc, 0.0f);
    }
    __syncthreads();
    if (t < 64) {
        float a2 = l2b[t];
        for (int i = 0; i < 128; i++) a2 = fmaf(s1[i], l2W[i * 64 + t], a2);
        s2[t] = fmaxf(a2, 0.0f);
    }
    __syncthreads();
    if (t < 10) {
        float a3 = l3b[t];
        for (int i = 0; i < 64; i++) a3 = fmaf(s2[i], l3W[i * 10 + t], a3);
        s3[t] = a3;
    }
    __syncthreads();
    if (t == 0) {
        float m = -1e30f;
        for (int c = 0; c < 10; c++) m = fmaxf(m, s3[c]);
        float sum = 0.0f;
        for (int c = 0; c < 10; c++) sum += expf(s3[c] - m);
        red[0] = m;
        red[1] = logf(sum);
    }
    __syncthreads();
    if (t < 10) out[g * 10 + t] = s3[t] - red[0] - red[1];
}

// ---------------------------------------------------------------------------
extern "C" void kernel_launch(void* const* d_in, const int* in_sizes, int n_in,
                              void* d_out, int out_size, void* d_ws, size_t ws_size,
                              hipStream_t stream) {
    const float* x    = (const float*)d_in[0];
    const int* src0   = (const int*)d_in[1];
    const int* dst0   = (const int*)d_in[2];
    const float* W1   = (const float*)d_in[3];
    const float* b1   = (const float*)d_in[4];
    const float* A1   = (const float*)d_in[5];
    const float* ps1W = (const float*)d_in[6];
    const float* ps1b = (const float*)d_in[7];
    const float* W2   = (const float*)d_in[8];
    const float* b2   = (const float*)d_in[9];
    const float* A2   = (const float*)d_in[10];
    const float* ps2W = (const float*)d_in[11];
    const float* ps2b = (const float*)d_in[12];
    const float* W3   = (const float*)d_in[13];
    const float* b3   = (const float*)d_in[14];
    const float* A3   = (const float*)d_in[15];
    const float* ps3W = (const float*)d_in[16];
    const float* ps3b = (const float*)d_in[17];
    const float* l1W  = (const float*)d_in[18];
    const float* l1b  = (const float*)d_in[19];
    const float* l2W  = (const float*)d_in[20];
    const float* l2b  = (const float*)d_in[21];
    const float* l3W  = (const float*)d_in[22];
    const float* l3b  = (const float*)d_in[23];
    float* out = (float*)d_out;

    char* ws = (char*)d_ws;
    size_t o = 0;
    auto alloc = [&](size_t bytes) -> void* {
        void* p = ws + o;
        o += (bytes + 255) & ~(size_t)255;
        return p;
    };
    float*    hproj = (float*)alloc((size_t)N0 * FDIM * 4);
    float*    hact  = (float*)alloc((size_t)N0 * FDIM * 4);
    int*      cntA  = (int*)alloc(N0 * 4);
    int*      cntB  = (int*)alloc(N1 * 4);
    int*      cntC  = (int*)alloc(N2 * 4);
    int*      slotA = (int*)alloc((size_t)N0 * CAP * 4);
    int*      slotB = (int*)alloc((size_t)N1 * CAP * 4);
    int*      slotC = (int*)alloc((size_t)N2 * CAP * 4);
    float*    cs    = (float*)alloc(N0 * 4);
    int*      nmapA = (int*)alloc(N0 * 4);
    int*      nmapB = (int*)alloc(N1 * 4);
    int*      perm  = (int*)alloc(N1 * 4);
    float*    mult  = (float*)alloc(N1 * 4);
    unsigned* rmax  = (unsigned*)alloc(2 * RSEC * 4);
    float*    rsum  = (float*)alloc(2 * RSEC * 4);

    // ---------------- Stage 1: n=32768, nper=1024, k=512 ----------------
    bin_proj1<<<BGR + N0 / 32, 256, 0, stream>>>(src0, dst0, cntA, slotA, x, W1,
                                                 hproj, rmax, rsum);
    agg_kernel<<<N0 / 4, 256, 0, stream>>>(hproj, b1, cntA, slotA, A1, ps1W, hact, cs, NPER0);
    topk_kernel<<<BGR, 1024, 0, stream>>>(cs, cntA, slotA, ps1b, NPER0, K1,
                                          nmapA, perm, mult);

    // ---------------- Stage 2 (+ stage-1 pooling readout) ----------------
    comp_proj_pool<<<N1 / 4 + N1 / 32 + BGR * K1 / 8, 256, 0, stream>>>(
        cntA, slotA, nmapA, cntB, slotB, hact, perm, mult, W2, hproj,
        N1 / 4, N1 / 32, K1, rmax, rsum);
    agg_kernel<<<N1 / 4, 256, 0, stream>>>(hproj, b2, cntB, slotB, A2, ps2W, hact, cs, K1);
    topk_kernel<<<BGR, 1024, 0, stream>>>(cs, cntB, slotB, ps2b, K1, K2,
                                          nmapB, perm, mult);

    // ---------------- Stage 3 (+ stage-2 pooling readout) ----------------
    comp_proj_pool<<<N2 / 4 + N2 / 32 + BGR * K2 / 8, 256, 0, stream>>>(
        cntB, slotB, nmapB, cntC, slotC, hact, perm, mult, W3, hproj,
        N2 / 4, N2 / 32, K2, rmax + RSEC, rsum + RSEC);
    agg_kernel<<<N2 / 4, 256, 0, stream>>>(hproj, b3, cntC, slotC, A3, ps3W, hact, cs, K2);
    topk_kernel<<<BGR, 1024, 0, stream>>>(cs, cntC, slotC, ps3b, K2, K3,
                                          nmapA /*unused*/, perm, mult);

    // ---------------- Stage-3 pooling + final MLP (fused) ----------------
    pool3_mlp<<<BGR, 1024, 0, stream>>>(hact, perm, mult, rmax, rsum,
                                        l1W, l1b, l2W, l2b, l3W, l3b, out);

    (void)in_sizes; (void)n_in; (void)out_size; (void)ws_size;
}

// Round 7
// 247.604 us; speedup vs baseline: 10.8435x; 1.0513x over previous
//
#include <hip/hip_runtime.h>
#include <math.h>

#define BGR 32
#define NPER0 1024
#define N0 (BGR * NPER0)
#define FDIM 128
#define EDG 524288
#define EPG (EDG / BGR)   // 16384 edges per graph (contiguous by construction)
#define EBLK (EDG / 256)  // 2048 edge-parallel binning blocks
#define K1 512
#define K2 256
#define K3 128
#define N1 (BGR * K1)
#define N2 (BGR * K2)
#define SXP 36            // sxT row pad (floats): 16B-aligned b128 reads
#define CAP 64            // slots per node (Poisson(16); P(deg>64) ~ 1e-18)
#define RSEC (BGR * FDIM)

// Order-preserving float<->uint encoding (radix keys + atomicMax readout).
__device__ __forceinline__ unsigned enc_f(float v) {
    unsigned u = __float_as_uint(v);
    return (u & 0x80000000u) ? ~u : (u | 0x80000000u);
}
__device__ __forceinline__ float dec_f(unsigned u) {
    return (u & 0x80000000u) ? __uint_as_float(u ^ 0x80000000u) : __uint_as_float(~u);
}

// ---------------------------------------------------------------------------
// Register-tiled projection compute: 32 nodes x 128 feats per tile;
// thread=(feature-quad, node-quad); 4x4 outer product, 2 ds_read_b128/k-step.
// ---------------------------------------------------------------------------
__device__ __forceinline__ void proj_compute(float* __restrict__ hp, int nb, int t,
                                             const float* __restrict__ sW,
                                             const float* __restrict__ sxT) {
    const int fg = t >> 3, ng = t & 7, h = fg >> 3;
    const float* ap = sxT + h * 32 * SXP + ng * 4;
    const float* bp = sW + h * 1024 + (fg & 7) * 4;
    float4 acc0 = {0.f, 0.f, 0.f, 0.f}, acc1 = acc0, acc2 = acc0, acc3 = acc0;
#pragma unroll
    for (int k = 0; k < 32; k++) {
        float4 a = *(const float4*)(ap + k * SXP);
        float4 b = *(const float4*)(bp + k * 32);
        acc0.x = fmaf(a.x, b.x, acc0.x); acc0.y = fmaf(a.x, b.y, acc0.y);
        acc0.z = fmaf(a.x, b.z, acc0.z); acc0.w = fmaf(a.x, b.w, acc0.w);
        acc1.x = fmaf(a.y, b.x, acc1.x); acc1.y = fmaf(a.y, b.y, acc1.y);
        acc1.z = fmaf(a.y, b.z, acc1.z); acc1.w = fmaf(a.y, b.w, acc1.w);
        acc2.x = fmaf(a.z, b.x, acc2.x); acc2.y = fmaf(a.z, b.y, acc2.y);
        acc2.z = fmaf(a.z, b.z, acc2.z); acc2.w = fmaf(a.z, b.w, acc2.w);
        acc3.x = fmaf(a.w, b.x, acc3.x); acc3.y = fmaf(a.w, b.y, acc3.y);
        acc3.z = fmaf(a.w, b.z, acc3.z); acc3.w = fmaf(a.w, b.w, acc3.w);
    }
    float4* op = (float4*)(hp + (size_t)(nb + ng * 4) * FDIM + fg * 4);
    op[0] = acc0; op[32] = acc1; op[64] = acc2; op[96] = acc3;
}

// ---------------------------------------------------------------------------
// Pooling readout (wide): 8 kept nodes per block, 256 threads=(f,half).
// ---------------------------------------------------------------------------
__device__ __forceinline__ void pool_body(const float* __restrict__ ha,
                                          const int* __restrict__ perm,
                                          const float* __restrict__ mult, int k, int pb,
                                          unsigned* __restrict__ rmax,
                                          float* __restrict__ rsum,
                                          float* __restrict__ smax,
                                          float* __restrict__ ssum) {
    const int t = threadIdx.x;
    const int g = pb & 31;
    const int c = pb >> 5;
    const int f = t & 127, half = t >> 7;
    const int base = g * k + c * 8;
    float vmax = -1e30f, vsum = 0.0f;
#pragma unroll
    for (int j0 = 0; j0 < 4; j0++) {
        int newid = base + half + j0 * 2;
        int old = perm[newid];
        float m = mult[newid];
        float v = ha[(size_t)old * FDIM + f] * m;
        vmax = fmaxf(vmax, v);
        vsum += v;
    }
    if (half) { smax[f] = vmax; ssum[f] = vsum; }
    __syncthreads();
    if (!half) {
        vmax = fmaxf(vmax, smax[f]);
        vsum += ssum[f];
        atomicMax(&rmax[g * FDIM + f], enc_f(vmax));
        atomicAdd(&rsum[g * FDIM + f], vsum);
    }
}

// ---------------------------------------------------------------------------
// K1: [0,EBLK) edge-parallel binning, graph-swizzled (graph g's cnt/slot
// atomics land on XCD g%8 where g's proj/agg also run); blocks 0..31 also
// zero the readout accumulators. [EBLK,...) proj1 tiles.
// cntA pre-zeroed by hipMemsetAsync.
// ---------------------------------------------------------------------------
__global__ void bin_proj1(const int* __restrict__ src, const int* __restrict__ dst,
                          int* __restrict__ cnt, int* __restrict__ slot,
                          const float* __restrict__ x, const float* __restrict__ W,
                          float* __restrict__ hp,
                          unsigned* __restrict__ rmax, float* __restrict__ rsum) {
    __shared__ __align__(16) float sW[4096];
    __shared__ __align__(16) float sxT[128 * SXP];
    const int t = threadIdx.x;
    if (blockIdx.x < EBLK) {
        if (blockIdx.x < BGR) {  // zero readout accumulators: 32*256 == 2*RSEC
            int z = blockIdx.x * 256 + t;
            rmax[z] = 0u;
            rsum[z] = 0.0f;
        }
        const int g = blockIdx.x & 31, chunk = blockIdx.x >> 5;
        int e = g * EPG + chunk * 256 + t;
        int s = src[e];
        int d = dst[e];
        int p = atomicAdd(&cnt[d], 1);
        if (p < CAP) slot[(size_t)d * CAP + p] = s;
        return;
    }
    const int tb = blockIdx.x - EBLK;
    const int nb = (tb & 31) * NPER0 + (tb >> 5) * 32;
    for (int i = t; i < 4096; i += 256) sW[i] = W[i];
    for (int i = t; i < 4096; i += 256) {
        int node = i >> 7, dim = i & 127;
        sxT[dim * SXP + node] = x[(size_t)(nb + node) * FDIM + dim];
    }
    __syncthreads();
    proj_compute(hp, nb, t, sW, sxT);
}

// ---------------------------------------------------------------------------
// Fat kernel (stages 2/3): comp (slot compaction) | proj (perm-gather) | pool.
// ---------------------------------------------------------------------------
__global__ void comp_proj_pool(const int* __restrict__ cnt_prev,
                               const int* __restrict__ slot_prev,
                               const int* __restrict__ nmap,
                               int* __restrict__ cnt_next, int* __restrict__ slot_next,
                               const float* __restrict__ ha, const int* __restrict__ perm,
                               const float* __restrict__ mult, const float* __restrict__ W,
                               float* __restrict__ hp, int ncomp, int ntiles, int kprev,
                               unsigned* __restrict__ rmax, float* __restrict__ rsum) {
    __shared__ __align__(16) float sW[4096];
    __shared__ __align__(16) float sxT[128 * SXP];
    const int t = threadIdx.x;
    if (blockIdx.x < ncomp) {
        const int w = t >> 6, lane = t & 63;
        const int b = (blockIdx.x & 31) * kprev + (blockIdx.x >> 5) * 4 + w;
        const int old = perm[b];
        const int c = min(cnt_prev[old], CAP);
        int a = -1;
        if (lane < c) a = nmap[slot_prev[(size_t)old * CAP + lane]];
        unsigned long long mk = __ballot(a >= 0);
        if (a >= 0) {
            int pos = __popcll(mk & ((1ull << lane) - 1ull));
            slot_next[(size_t)b * CAP + pos] = a;
        }
        if (lane == 0) cnt_next[b] = __popcll(mk);
        return;
    }
    if (blockIdx.x >= ncomp + ntiles) {
        pool_body(ha, perm, mult, kprev, blockIdx.x - (ncomp + ntiles), rmax, rsum,
                  sW, sW + 128);
        return;
    }
    const int tb = blockIdx.x - ncomp;
    const int nb = (tb & 31) * kprev + (tb >> 5) * 32;
    for (int i = t; i < 4096; i += 256) sW[i] = W[i];
    for (int i = t; i < 4096; i += 256) {
        int node = i >> 7, dim = i & 127;
        int newid = nb + node;
        sxT[dim * SXP + node] = ha[(size_t)perm[newid] * FDIM + dim] * mult[newid];
    }
    __syncthreads();
    proj_compute(hp, nb, t, sW, sxT);
}

// ---------------------------------------------------------------------------
// GCN aggregation (gather via slots) + bias + relu + fused attention partial.
// Wave per node; lane = 2 features (float2); shfl-broadcast edge prefetch.
// Writes csd[i] = cs_raw[i] * dinv[i].
// ---------------------------------------------------------------------------
__global__ void agg_kernel(const float* __restrict__ hp, const float* __restrict__ b,
                           const int* __restrict__ cnt, const int* __restrict__ slot,
                           const float* __restrict__ A, const float* __restrict__ psW,
                           float* __restrict__ ha, float* __restrict__ csd, int nper) {
    const int w = threadIdx.x >> 6;
    const int lane = threadIdx.x & 63;
    const int g = blockIdx.x & 31;
    const int chunk = blockIdx.x >> 5;
    const int i = g * nper + chunk * 4 + w;
    const int ci = cnt[i];
    const float di = rsqrtf((float)ci + 1.0f);
    const int c = min(ci, CAP);
    const float2* __restrict__ hp2 = (const float2*)hp;
    float2 self = hp2[(size_t)i * 64 + lane];
    float accx = self.x * di * di, accy = self.y * di * di;
    int idx = 0;
    float dv = 0.0f;
    if (lane < c) {
        idx = slot[i * CAP + lane];
        dv = rsqrtf((float)cnt[idx] + 1.0f);
    }
    int j = 0;
    for (; j + 3 < c; j += 4) {
        int s0 = __shfl(idx, j, 64);
        int s1 = __shfl(idx, j + 1, 64);
        int s2 = __shfl(idx, j + 2, 64);
        int s3 = __shfl(idx, j + 3, 64);
        float c0 = __shfl(dv, j, 64) * di;
        float c1 = __shfl(dv, j + 1, 64) * di;
        float c2 = __shfl(dv, j + 2, 64) * di;
        float c3 = __shfl(dv, j + 3, 64) * di;
        float2 v0 = hp2[(size_t)s0 * 64 + lane];
        float2 v1 = hp2[(size_t)s1 * 64 + lane];
        float2 v2 = hp2[(size_t)s2 * 64 + lane];
        float2 v3 = hp2[(size_t)s3 * 64 + lane];
        accx = fmaf(v0.x, c0, accx); accy = fmaf(v0.y, c0, accy);
        accx = fmaf(v1.x, c1, accx); accy = fmaf(v1.y, c1, accy);
        accx = fmaf(v2.x, c2, accx); accy = fmaf(v2.y, c2, accy);
        accx = fmaf(v3.x, c3, accx); accy = fmaf(v3.y, c3, accy);
    }
    for (; j < c; j++) {
        int s = __shfl(idx, j, 64);
        float co = __shfl(dv, j, 64) * di;
        float2 v = hp2[(size_t)s * 64 + lane];
        accx = fmaf(v.x, co, accx); accy = fmaf(v.y, co, accy);
    }
    float2 bb = ((const float2*)b)[lane];
    float2 o;
    o.x = fmaxf(accx + bb.x, 0.0f);
    o.y = fmaxf(accy + bb.y, 0.0f);
    ((float2*)ha)[(size_t)i * 64 + lane] = o;
    float2 Av = ((const float2*)A)[lane];
    float2 Pv = ((const float2*)psW)[lane];
    float a = o.x * Av.x + o.y * Av.y;
    float p = o.x * Pv.x + o.y * Pv.y;
#pragma unroll
    for (int d = 8; d > 0; d >>= 1) {
        a += __shfl_down(a, d, 16);
        p += __shfl_down(p, d, 16);
    }
    float part = a * p;                  // heads at lanes 0,16,32,48
    part += __shfl_down(part, 16, 64);
    part += __shfl_down(part, 32, 64);
    if (lane == 0) csd[i] = part * di;   // pre-scaled by dinv[i]
}

// ---------------------------------------------------------------------------
// Top-k with INLINE score: 1024 threads, one block per graph. csd staged in
// LDS; each thread scores its node (slot row global, csd lookups LDS), then
// 4-pass radix select with wave equal-digit pre-merge.
// ---------------------------------------------------------------------------
__global__ __launch_bounds__(1024) void topk_kernel(
        const float* __restrict__ csd, const int* __restrict__ cnt,
        const int* __restrict__ slot, const float* __restrict__ psb,
        int nper, int k, int* __restrict__ nmap, int* __restrict__ perm,
        float* __restrict__ mult) {
    __shared__ float cs_l[NPER0];
    __shared__ float sc[NPER0];
    __shared__ unsigned ukey[NPER0];
    __shared__ unsigned hist[256];
    __shared__ unsigned wtot[4];
    __shared__ unsigned sel[2];
    __shared__ int ctr[2];
    const int g = blockIdx.x, t = threadIdx.x;
    const int gnb = g * nper;
    if (t < nper) cs_l[t] = csd[gnb + t];
    if (t == 0) { sel[0] = 0u; sel[1] = (unsigned)k; }
    __syncthreads();
    if (t < nper) {
        int ci = cnt[gnb + t];
        int c = min(ci, CAP);
        const int* srow = slot + (size_t)(gnb + t) * CAP;
        float v = 0.0f;
        for (int j = 0; j < c; j++) v += cs_l[srow[j] - gnb];
        float s = rsqrtf((float)ci + 1.0f) * (v + cs_l[t]) + psb[0];
        sc[t] = s;
        ukey[t] = enc_f(s);
    }
    __syncthreads();
    const int w4 = t >> 6, l = t & 63;
    for (int shift = 24; shift >= 0; shift -= 8) {
        if (t < 256) hist[t] = 0u;
        __syncthreads();
        const unsigned prefix = sel[0];
        const unsigned need = sel[1];
        {   // histogram with wave equal-digit pre-merge
            unsigned u = (t < nper) ? ukey[t] : 0u;
            bool inp = (t < nper) &&
                       ((shift == 24) || ((u >> (shift + 8)) == (prefix >> (shift + 8))));
            int dig = inp ? (int)((u >> shift) & 255u) : -1;
            int cv = inp ? 1 : 0;
#pragma unroll
            for (int d = 1; d < 64; d <<= 1) {
                int od = __shfl_xor(dig, d, 64);
                int oc = __shfl_xor(cv, d, 64);
                if (od == dig) cv = ((l & d) == 0) ? (cv + oc) : 0;
            }
            if (dig >= 0 && cv > 0) atomicAdd(&hist[dig], (unsigned)cv);
        }
        __syncthreads();
        unsigned h = 0, s = 0;
        if (t < 256) {
            h = hist[t];
            s = h;
#pragma unroll
            for (int off = 1; off < 64; off <<= 1) {
                unsigned v2 = __shfl_down(s, off, 64);
                if (l + off < 64) s += v2;
            }
            if (l == 0) wtot[w4] = s;
        }
        __syncthreads();
        if (t < 256) {
            unsigned add = 0;
            for (int ww = w4 + 1; ww < 4; ww++) add += wtot[ww];
            const unsigned sfx = s + add;   // #keys with digit >= t (within prefix)
            const unsigned gtr = sfx - h;   // #keys with digit >  t
            if (sfx >= need && gtr < need) {  // exactly one thread
                sel[0] = prefix | ((unsigned)t << shift);
                sel[1] = need - gtr;
            }
        }
        __syncthreads();
    }
    const unsigned T = sel[0];
    const int need2 = (int)sel[1];
    if (t == 0) { ctr[0] = 0; ctr[1] = k - need2; }
    __syncthreads();
    if (t < nper) {
        unsigned u = ukey[t];
        int newid = -1;
        if (u > T) {
            newid = atomicAdd(&ctr[0], 1);
        } else if (u == T) {
            int s2 = atomicAdd(&ctr[1], 1);
            if (s2 < k) newid = s2;
        }
        nmap[gnb + t] = (newid >= 0) ? g * k + newid : -1;
        if (newid >= 0) {
            perm[g * k + newid] = gnb + t;
            mult[g * k + newid] = tanhf(sc[t]);
        }
    }
}

// ---------------------------------------------------------------------------
// Final: stage-3 pooling (block-local, 1024 threads) + MLP + log_softmax.
// ---------------------------------------------------------------------------
__global__ __launch_bounds__(1024) void pool3_mlp(
        const float* __restrict__ ha, const int* __restrict__ perm,
        const float* __restrict__ mult,
        const unsigned* __restrict__ rmax, const float* __restrict__ rsum,
        const float* __restrict__ l1W, const float* __restrict__ l1b,
        const float* __restrict__ l2W, const float* __restrict__ l2b,
        const float* __restrict__ l3W, const float* __restrict__ l3b,
        float* __restrict__ out) {
    __shared__ float pm[8][FDIM], ps[8][FDIM];
    __shared__ float sz[256], s1[128], s2[64], s3[16], red[2];
    const int g = blockIdx.x, t = threadIdx.x;
    const int f = t & 127, ch = t >> 7;
    float vmax = -1e30f, vsum = 0.0f;
#pragma unroll
    for (int j = 0; j < K3 / 8; j++) {
        int nid = g * K3 + ch + j * 8;
        int old = perm[nid];
        float m = mult[nid];
        float v = ha[(size_t)old * FDIM + f] * m;
        vmax = fmaxf(vmax, v);
        vsum += v;
    }
    pm[ch][f] = vmax;
    ps[ch][f] = vsum;
    __syncthreads();
    if (t < 128) {
        float M = pm[0][t];
#pragma unroll
        for (int c2 = 1; c2 < 8; c2++) M = fmaxf(M, pm[c2][t]);
        sz[t] = dec_f(rmax[g * FDIM + t]) + dec_f(rmax[RSEC + g * FDIM + t]) + M;
    } else if (t < 256) {
        int f2 = t - 128;
        float S = ps[0][f2];
#pragma unroll
        for (int c2 = 1; c2 < 8; c2++) S += ps[c2][f2];
        sz[t] = rsum[g * FDIM + f2] / (float)K1 + rsum[RSEC + g * FDIM + f2] / (float)K2 +
                S / (float)K3;
    }
    __syncthreads();
    if (t < 128) {
        float acc = l1b[t];
        for (int i = 0; i < 256; i++) acc = fmaf(sz[i], l1W[i * 128 + t], acc);
        s1[t] = fmaxf(acc, 0.0f);
    }
    __syncthreads();
    if (t < 64) {
        float a2 = l2b[t];
        for (int i = 0; i < 128; i++) a2 = fmaf(s1[i], l2W[i * 64 + t], a2);
        s2[t] = fmaxf(a2, 0.0f);
    }
    __syncthreads();
    if (t < 10) {
        float a3 = l3b[t];
        for (int i = 0; i < 64; i++) a3 = fmaf(s2[i], l3W[i * 10 + t], a3);
        s3[t] = a3;
    }
    __syncthreads();
    if (t == 0) {
        float m = -1e30f;
        for (int c = 0; c < 10; c++) m = fmaxf(m, s3[c]);
        float sum = 0.0f;
        for (int c = 0; c < 10; c++) sum += expf(s3[c] - m);
        red[0] = m;
        red[1] = logf(sum);
    }
    __syncthreads();
    if (t < 10) out[g * 10 + t] = s3[t] - red[0] - red[1];
}

// ---------------------------------------------------------------------------
extern "C" void kernel_launch(void* const* d_in, const int* in_sizes, int n_in,
                              void* d_out, int out_size, void* d_ws, size_t ws_size,
                              hipStream_t stream) {
    const float* x    = (const float*)d_in[0];
    const int* src0   = (const int*)d_in[1];
    const int* dst0   = (const int*)d_in[2];
    const float* W1   = (const float*)d_in[3];
    const float* b1   = (const float*)d_in[4];
    const float* A1   = (const float*)d_in[5];
    const float* ps1W = (const float*)d_in[6];
    const float* ps1b = (const float*)d_in[7];
    const float* W2   = (const float*)d_in[8];
    const float* b2   = (const float*)d_in[9];
    const float* A2   = (const float*)d_in[10];
    const float* ps2W = (const float*)d_in[11];
    const float* ps2b = (const float*)d_in[12];
    const float* W3   = (const float*)d_in[13];
    const float* b3   = (const float*)d_in[14];
    const float* A3   = (const float*)d_in[15];
    const float* ps3W = (const float*)d_in[16];
    const float* ps3b = (const float*)d_in[17];
    const float* l1W  = (const float*)d_in[18];
    const float* l1b  = (const float*)d_in[19];
    const float* l2W  = (const float*)d_in[20];
    const float* l2b  = (const float*)d_in[21];
    const float* l3W  = (const float*)d_in[22];
    const float* l3b  = (const float*)d_in[23];
    float* out = (float*)d_out;

    char* ws = (char*)d_ws;
    size_t o = 0;
    auto alloc = [&](size_t bytes) -> void* {
        void* p = ws + o;
        o += (bytes + 255) & ~(size_t)255;
        return p;
    };
    float*    hproj = (float*)alloc((size_t)N0 * FDIM * 4);
    float*    hact  = (float*)alloc((size_t)N0 * FDIM * 4);
    int*      cntA  = (int*)alloc(N0 * 4);
    int*      cntB  = (int*)alloc(N1 * 4);
    int*      cntC  = (int*)alloc(N2 * 4);
    int*      slotA = (int*)alloc((size_t)N0 * CAP * 4);
    int*      slotB = (int*)alloc((size_t)N1 * CAP * 4);
    int*      slotC = (int*)alloc((size_t)N2 * CAP * 4);
    float*    cs    = (float*)alloc(N0 * 4);
    int*      nmapA = (int*)alloc(N0 * 4);
    int*      nmapB = (int*)alloc(N1 * 4);
    int*      perm  = (int*)alloc(N1 * 4);
    float*    mult  = (float*)alloc(N1 * 4);
    unsigned* rmax  = (unsigned*)alloc(2 * RSEC * 4);
    float*    rsum  = (float*)alloc(2 * RSEC * 4);

    // ---------------- Stage 1: n=32768, nper=1024, k=512 ----------------
    hipMemsetAsync(cntA, 0, N0 * 4, stream);
    bin_proj1<<<EBLK + N0 / 32, 256, 0, stream>>>(src0, dst0, cntA, slotA, x, W1,
                                                  hproj, rmax, rsum);
    agg_kernel<<<N0 / 4, 256, 0, stream>>>(hproj, b1, cntA, slotA, A1, ps1W, hact, cs, NPER0);
    topk_kernel<<<BGR, 1024, 0, stream>>>(cs, cntA, slotA, ps1b, NPER0, K1,
                                          nmapA, perm, mult);

    // ---------------- Stage 2 (+ stage-1 pooling readout) ----------------
    comp_proj_pool<<<N1 / 4 + N1 / 32 + BGR * K1 / 8, 256, 0, stream>>>(
        cntA, slotA, nmapA, cntB, slotB, hact, perm, mult, W2, hproj,
        N1 / 4, N1 / 32, K1, rmax, rsum);
    agg_kernel<<<N1 / 4, 256, 0, stream>>>(hproj, b2, cntB, slotB, A2, ps2W, hact, cs, K1);
    topk_kernel<<<BGR, 1024, 0, stream>>>(cs, cntB, slotB, ps2b, K1, K2,
                                          nmapB, perm, mult);

    // ---------------- Stage 3 (+ stage-2 pooling readout) ----------------
    comp_proj_pool<<<N2 / 4 + N2 / 32 + BGR * K2 / 8, 256, 0, stream>>>(
        cntB, slotB, nmapB, cntC, slotC, hact, perm, mult, W3, hproj,
        N2 / 4, N2 / 32, K2, rmax + RSEC, rsum + RSEC);
    agg_kernel<<<N2 / 4, 256, 0, stream>>>(hproj, b3, cntC, slotC, A3, ps3W, hact, cs, K2);
    topk_kernel<<<BGR, 1024, 0, stream>>>(cs, cntC, slotC, ps3b, K2, K3,
                                          nmapA /*unused*/, perm, mult);

    // ---------------- Stage-3 pooling + final MLP (fused) ----------------
    pool3_mlp<<<BGR, 1024, 0, stream>>>(hact, perm, mult, rmax, rsum,
                                        l1W, l1b, l2W, l2b, l3W, l3b, out);

    (void)in_sizes; (void)n_in; (void)out_size; (void)ws_size;
}